// Round 7
// baseline (2759.182 us; speedup 1.0000x reference)
//
#include <hip/hip_runtime.h>
#include <hip/hip_bf16.h>

#define N_NODES 20000
#define N_EDGES 320000

typedef __attribute__((ext_vector_type(8))) short shortx8;
typedef __attribute__((ext_vector_type(4))) float floatx4;
using bf16 = __hip_bfloat16;

typedef __attribute__((address_space(1))) const unsigned int GuT;
typedef __attribute__((address_space(3))) unsigned int LuT;
__device__ __forceinline__ void gl2lds16(const bf16* g, bf16* l) {
  __builtin_amdgcn_global_load_lds((GuT*)g, (LuT*)l, 16, 0, 0);
}

__device__ inline float b2f(unsigned short u) {
  union { unsigned int i; float f; } x;
  x.i = ((unsigned int)u) << 16;
  return x.f;
}
__device__ inline unsigned short f2b(float f) {
  bf16 h(f);
  return *(unsigned short*)&h;
}

struct APtrs { const bf16* p[6]; };

// ---------------- graph prep ----------------

__global__ void zero_kernel(int* p, int n) {
  int i = blockIdx.x * 256 + threadIdx.x;
  if (i < n) p[i] = 0;
}

__global__ void deg_kernel(const int* __restrict__ row, const int* __restrict__ col,
                           int* __restrict__ deg, int nE) {
  int e = blockIdx.x * 256 + threadIdx.x;
  if (e >= nE) return;
  int r = row[e], c = col[e];
  if (r != c) atomicAdd(&deg[r], 1);
}

__global__ void dis_kernel(const int* __restrict__ deg, float* __restrict__ dis, int n) {
  int i = blockIdx.x * 256 + threadIdx.x;
  if (i >= n) return;
  int d = deg[i];
  dis[i] = (d > 0) ? (1.0f / sqrtf((float)d)) : 0.0f;
}

__global__ __launch_bounds__(1024) void scan_kernel(const int* __restrict__ deg,
                                                    int* __restrict__ row_ptr,
                                                    int* __restrict__ cursor, int n) {
  __shared__ int part[1024];
  int t = threadIdx.x;
  int base = t * 20;
  int loc[20];
  int s = 0;
#pragma unroll
  for (int i = 0; i < 20; i++) {
    int idx = base + i;
    int v = (idx < n) ? deg[idx] : 0;
    loc[i] = s;
    s += v;
  }
  part[t] = s;
  __syncthreads();
  for (int offd = 1; offd < 1024; offd <<= 1) {
    int v = (t >= offd) ? part[t - offd] : 0;
    __syncthreads();
    part[t] += v;
    __syncthreads();
  }
  int basev = (t > 0) ? part[t - 1] : 0;
#pragma unroll
  for (int i = 0; i < 20; i++) {
    int idx = base + i;
    if (idx < n) {
      int rp = basev + loc[i];
      row_ptr[idx] = rp;
      cursor[idx] = rp;
    }
  }
  if (t == 1023) row_ptr[n] = part[1023];
}

__global__ void scatter_kernel(const int* __restrict__ row, const int* __restrict__ col,
                               const float* __restrict__ dis, int* __restrict__ cursor,
                               int* __restrict__ col_s, float* __restrict__ w_s, int nE) {
  int e = blockIdx.x * 256 + threadIdx.x;
  if (e >= nE) return;
  int r = row[e], c = col[e];
  if (r == c) return;
  int p = atomicAdd(&cursor[r], 1);
  col_s[p] = c;
  w_s[p] = -dis[r] * dis[c];
}

// ---------------- weight prep: W (K,I,J) fp32 -> Wt[k][j][i] bf16 ----------------

__global__ void wtrans_kernel(const float* __restrict__ W, bf16* __restrict__ Wt,
                              int K_, int I, int J) {
  __shared__ float tile[32][33];
  int jt = blockIdx.x % (J / 32);
  int rest = blockIdx.x / (J / 32);
  int it = rest % (I / 32);
  int k = rest / (I / 32);
  int tx = threadIdx.x, ty = threadIdx.y;
  const float* src = W + (size_t)k * I * J;
  for (int r = ty; r < 32; r += 8)
    tile[r][tx] = src[(size_t)(it * 32 + r) * J + jt * 32 + tx];
  __syncthreads();
  for (int r = ty; r < 32; r += 8) {
    int j = jt * 32 + r;
    Wt[((size_t)k * J + j) * I + it * 32 + tx] = bf16(tile[tx][r]);
  }
}

// ---------------- cast x (fp32 flat) -> bf16 ----------------

__global__ void cast_x_kernel(const float* __restrict__ x, bf16* __restrict__ dst, int n4) {
  int idx = blockIdx.x * 256 + threadIdx.x;
  if (idx >= n4) return;
  int flat = idx * 4;
  float4 v = *(const float4*)(x + flat);
  dst[flat + 0] = bf16(v.x);
  dst[flat + 1] = bf16(v.y);
  dst[flat + 2] = bf16(v.z);
  dst[flat + 3] = bf16(v.w);
}

// ---------------- XCD-sliced prop for F=1152 ----------------
// Gathers only a 96-feature column slice per block; chunk pinned to an XCD via
// blockIdx&mask so the 20000x96x2B = 3.84MB source slab stays L2-resident.
// Block = 256 threads = 4 waves; wave w handles node g*4+w; lanes 0..47 cover
// 96 feats as ushort2. tx0 (may alias dst) and dst use non-temporal accesses
// so streaming traffic doesn't evict the gather slab.

template <int LOGC>
__global__ __launch_bounds__(256) void prop_slice_kernel(
    const int* __restrict__ row_ptr, const int* __restrict__ col_s,
    const float* __restrict__ w_s, const bf16* __restrict__ src,
    const bf16* tx0, bf16* dst, int fbase) {
  constexpr int CH = 1 << LOGC;
  int g = blockIdx.x >> LOGC;
  int c = blockIdx.x & (CH - 1);
  int wave = threadIdx.x >> 6;
  int lane = threadIdx.x & 63;
  int node = g * 4 + wave;
  bool act = lane < 48;
  int fb = fbase + c * 96 + lane * 2;
  int e0 = row_ptr[node], e1 = row_ptr[node + 1];
  float a0 = 0.0f, a1 = 0.0f;
  const unsigned short* sp = (const unsigned short*)src;

  int e = e0;
  for (; e + 16 <= e1; e += 16) {
    int cs[16];
    float wv[16];
#pragma unroll
    for (int u = 0; u < 16; u++) {
      cs[u] = col_s[e + u];
      wv[u] = w_s[e + u];
    }
    if (act) {
      ushort2 v[16];
#pragma unroll
      for (int u = 0; u < 16; u++) v[u] = *(const ushort2*)(sp + (size_t)cs[u] * 1152 + fb);
#pragma unroll
      for (int u = 0; u < 16; u++) {
        a0 += wv[u] * b2f(v[u].x);
        a1 += wv[u] * b2f(v[u].y);
      }
    }
  }
  for (; e + 4 <= e1; e += 4) {
    int cs[4];
    float wv[4];
#pragma unroll
    for (int u = 0; u < 4; u++) {
      cs[u] = col_s[e + u];
      wv[u] = w_s[e + u];
    }
    if (act) {
      ushort2 v[4];
#pragma unroll
      for (int u = 0; u < 4; u++) v[u] = *(const ushort2*)(sp + (size_t)cs[u] * 1152 + fb);
#pragma unroll
      for (int u = 0; u < 4; u++) {
        a0 += wv[u] * b2f(v[u].x);
        a1 += wv[u] * b2f(v[u].y);
      }
    }
  }
  for (; e < e1; e++) {
    int cc = col_s[e];
    float w = w_s[e];
    if (act) {
      ushort2 v = *(const ushort2*)(sp + (size_t)cc * 1152 + fb);
      a0 += w * b2f(v.x);
      a1 += w * b2f(v.y);
    }
  }

  if (!act) return;
  unsigned int* dp = (unsigned int*)((unsigned short*)dst + (size_t)node * 1152 + fb);
  ushort2 o;
  if (tx0) {
    const unsigned int* t0 =
        (const unsigned int*)((const unsigned short*)tx0 + (size_t)node * 1152 + fb);
    unsigned int tvu = __builtin_nontemporal_load(t0);
    ushort2 tv = *(ushort2*)&tvu;
    o.x = f2b(2.0f * a0 - b2f(tv.x));
    o.y = f2b(2.0f * a1 - b2f(tv.y));
  } else {
    o.x = f2b(a0);
    o.y = f2b(a1);
  }
  __builtin_nontemporal_store(*(unsigned int*)&o, dp);
}

// ---------------- generic prop (kept for F=576) ----------------

template <int F, int VEC>
__global__ __launch_bounds__(320) void prop_kernel(
    const int* __restrict__ row_ptr, const int* __restrict__ col_s,
    const float* __restrict__ w_s, const bf16* __restrict__ src,
    const bf16* tx0, bf16* dst) {
  constexpr int C = F / VEC;
  int node = blockIdx.x;
  int t = threadIdx.x;
  bool act = t < C;
  int fb = t * VEC;
  int e0 = row_ptr[node], e1 = row_ptr[node + 1];
  float acc[VEC];
#pragma unroll
  for (int q = 0; q < VEC; q++) acc[q] = 0.0f;

  const unsigned short* sp = (const unsigned short*)src;
  int e = e0;
  for (; e + 16 <= e1; e += 16) {
    int cs[16];
    float wv[16];
#pragma unroll
    for (int u = 0; u < 16; u++) {
      cs[u] = col_s[e + u];
      wv[u] = w_s[e + u];
    }
    if (act) {
      ushort2 v[16];
#pragma unroll
      for (int u = 0; u < 16; u++) v[u] = *(const ushort2*)(sp + (size_t)cs[u] * F + fb);
#pragma unroll
      for (int u = 0; u < 16; u++) {
        acc[0] += wv[u] * b2f(v[u].x);
        acc[1] += wv[u] * b2f(v[u].y);
      }
    }
  }
  for (; e + 4 <= e1; e += 4) {
    int cs[4];
    float wv[4];
#pragma unroll
    for (int u = 0; u < 4; u++) {
      cs[u] = col_s[e + u];
      wv[u] = w_s[e + u];
    }
    if (act) {
      ushort2 v[4];
#pragma unroll
      for (int u = 0; u < 4; u++) v[u] = *(const ushort2*)(sp + (size_t)cs[u] * F + fb);
#pragma unroll
      for (int u = 0; u < 4; u++) {
        acc[0] += wv[u] * b2f(v[u].x);
        acc[1] += wv[u] * b2f(v[u].y);
      }
    }
  }
  for (; e < e1; e++) {
    int c = col_s[e];
    float w = w_s[e];
    if (act) {
      ushort2 v = *(const ushort2*)(sp + (size_t)c * F + fb);
      acc[0] += w * b2f(v.x);
      acc[1] += w * b2f(v.y);
    }
  }

  if (!act) return;
  unsigned short* dp = (unsigned short*)dst + (size_t)node * F + fb;
  if (tx0) {
    const unsigned short* t0 = (const unsigned short*)tx0 + (size_t)node * F + fb;
    ushort2 tv = *(const ushort2*)t0;
    ushort2 o;
    o.x = f2b(2.0f * acc[0] - b2f(tv.x));
    o.y = f2b(2.0f * acc[1] - b2f(tv.y));
    *(ushort2*)dp = o;
  } else {
    ushort2 o;
    o.x = f2b(acc[0]);
    o.y = f2b(acc[1]);
    *(ushort2*)dp = o;
  }
}

// ---------------- bf16 MFMA GEMM (m97 structure), multi-segment, XCD-swizzled ------

template <int MODE, int NSEG>
__global__ __launch_bounds__(256) void gemm_kernel(
    APtrs ap, const bf16* __restrict__ Bbase,
    const float* __restrict__ bias, float* __restrict__ accbuf,
    void* __restrict__ dst, int M, int Nout, int Kt, int dstLd) {
  __shared__ bf16 As[128 * 32];
  __shared__ bf16 Bs[128 * 32];
  int nb = (Nout + 127) >> 7;
  int mtiles = (M + 127) >> 7;
  int xcd = blockIdx.x & 7;
  int s = blockIdx.x >> 3;
  int bn = s % nb;
  int bm = (s / nb) * 8 + xcd;
  if (bm >= mtiles) return;
  int m0 = bm << 7, n0 = bn << 7;
  int t = threadIdx.x;
  int lane = t & 63;
  int wave = t >> 6;
  int wm = wave & 1, wn = wave >> 1;
  int l16 = lane & 15;
  int k8 = (lane >> 4) << 3;
  floatx4 acc[4][4] = {};

  int srow = lane >> 2;
  int scol = (lane & 3) << 3;

#pragma unroll
  for (int seg = 0; seg < NSEG; seg++) {
    const bf16* A = ap.p[seg];
    const bf16* Bt = Bbase + (size_t)seg * Nout * Kt;
#pragma unroll 1
    for (int kt = 0; kt < Kt; kt += 32) {
#pragma unroll
      for (int q = 0; q < 2; q++) {
        int inst = (wave << 1) + q;
        int r = (inst << 4) + srow;
        int ga = m0 + r;
        if (ga < M)
          gl2lds16(A + (size_t)ga * Kt + kt + scol, &As[inst << 9]);
        int gb = n0 + r;
        if (gb < Nout)
          gl2lds16(Bt + (size_t)gb * Kt + kt + scol, &Bs[inst << 9]);
      }
      __syncthreads();
      shortx8 af[4], bfr[4];
#pragma unroll
      for (int i = 0; i < 4; i++)
        af[i] = *(const shortx8*)&As[(((wm << 6) + (i << 4) + l16) << 5) + k8];
#pragma unroll
      for (int j = 0; j < 4; j++)
        bfr[j] = *(const shortx8*)&Bs[(((wn << 6) + (j << 4) + l16) << 5) + k8];
#pragma unroll
      for (int i = 0; i < 4; i++)
#pragma unroll
        for (int j = 0; j < 4; j++)
          acc[i][j] = __builtin_amdgcn_mfma_f32_16x16x32_bf16(af[i], bfr[j], acc[i][j], 0, 0, 0);
      __syncthreads();
    }
  }

  int lq = lane >> 4;
#pragma unroll
  for (int j = 0; j < 4; j++) {
    int colg = n0 + (wn << 6) + (j << 4) + l16;
    if (colg >= Nout) continue;
    float bv = (MODE == 0 || MODE == 4 || MODE == 5) ? bias[colg] : 0.0f;
#pragma unroll
    for (int i = 0; i < 4; i++) {
      int rowb = m0 + (wm << 6) + (i << 4) + (lq << 2);
#pragma unroll
      for (int q = 0; q < 4; q++) {
        int rowg = rowb + q;
        if (rowg >= M) continue;
        float v = acc[i][j][q];
        size_t aidx = (size_t)rowg * Nout + colg;
        if constexpr (MODE == 0) {
          accbuf[aidx] = v + bv;
        } else if constexpr (MODE == 1) {
          accbuf[aidx] += v;
        } else if constexpr (MODE == 2) {
          float s2 = fmaxf(accbuf[aidx] + v, 0.0f);
          ((bf16*)dst)[(size_t)rowg * dstLd + colg] = bf16(s2);
        } else if constexpr (MODE == 3) {
          float s2 = fmaxf(accbuf[aidx] + v, 0.0f);
          ((float*)dst)[(size_t)rowg * Nout + colg] = s2;
        } else if constexpr (MODE == 4) {
          float s2 = fmaxf(v + bv, 0.0f);
          ((bf16*)dst)[(size_t)rowg * dstLd + colg] = bf16(s2);
        } else {
          float s2 = fmaxf(v + bv, 0.0f);
          ((float*)dst)[(size_t)rowg * Nout + colg] = s2;
        }
      }
    }
  }
}

// ---------------- host launch ----------------

extern "C" void kernel_launch(void* const* d_in, const int* in_sizes, int n_in,
                              void* d_out, int out_size, void* d_ws, size_t ws_size,
                              hipStream_t stream) {
  const float* x = (const float*)d_in[0];
  const int* row = (const int*)d_in[1];
  const int* col = (const int*)d_in[2];
  const float* W1 = (const float*)d_in[3];
  const float* b1 = (const float*)d_in[4];
  const float* W2 = (const float*)d_in[5];
  const float* b2 = (const float*)d_in[6];
  const float* W3 = (const float*)d_in[7];
  const float* b3 = (const float*)d_in[8];

  char* ws = (char*)d_ws;
  size_t off = 0;
  auto alloc = [&](size_t bytes) -> void* {
    void* p = ws + off;
    off += (bytes + 255) & ~(size_t)255;
    return p;
  };

  const size_t TXB = (size_t)N_NODES * 1152 * 2;
  bf16* Wt = (bf16*)alloc((size_t)6 * 1152 * 1152 * 2);
  int* deg = (int*)alloc(N_NODES * 4);
  float* dis = (float*)alloc(N_NODES * 4);
  int* row_ptr = (int*)alloc((N_NODES + 1) * 4);
  int* cursor = (int*)alloc(N_NODES * 4);
  int* col_s = (int*)alloc(N_EDGES * 4);
  float* w_s = (float*)alloc(N_EDGES * 4);
  size_t off_common = off;

  size_t need_A = off_common + 7 * ((TXB + 255) & ~(size_t)255);
  size_t need_B = off_common + 3 * ((TXB + 255) & ~(size_t)255) +
                  (((size_t)N_NODES * 1152 * 4 + 255) & ~(size_t)255);
  int tier = (ws_size >= need_A) ? 0 : (ws_size >= need_B) ? 1 : 2;

  zero_kernel<<<(N_NODES + 255) / 256, 256, 0, stream>>>(deg, N_NODES);
  deg_kernel<<<(N_EDGES + 255) / 256, 256, 0, stream>>>(row, col, deg, N_EDGES);
  dis_kernel<<<(N_NODES + 255) / 256, 256, 0, stream>>>(deg, dis, N_NODES);
  scan_kernel<<<1, 1024, 0, stream>>>(deg, row_ptr, cursor, N_NODES);
  scatter_kernel<<<(N_EDGES + 255) / 256, 256, 0, stream>>>(row, col, dis, cursor,
                                                            col_s, w_s, N_EDGES);

  const int MT = (N_NODES + 127) >> 7;
  const int GMT = 8 * ((MT + 7) >> 3);  // 160
  const bf16* NB = nullptr;
  const int NX = N_NODES * 1152 / 4;

  // XCD-sliced big prop: pass A = chunks 0-7 (feats 0-767), pass B = chunks
  // 8-11 (feats 768-1151); chunk pinned to XCD via blockIdx low bits.
  auto prop1152 = [&](const bf16* src, const bf16* tx0, bf16* dst) {
    prop_slice_kernel<3><<<(N_NODES / 4) * 8, 256, 0, stream>>>(row_ptr, col_s, w_s,
                                                                src, tx0, dst, 0);
    prop_slice_kernel<2><<<(N_NODES / 4) * 4, 256, 0, stream>>>(row_ptr, col_s, w_s,
                                                                src, tx0, dst, 768);
  };

  if (tier == 0) {
    // ================= Tier A: batched-K, no accumulator =================
    bf16* T[7];
    for (int i = 0; i < 7; i++) T[i] = (bf16*)alloc(TXB);

    // layer 1: K=6, 1152 -> 1152
    wtrans_kernel<<<6 * 36 * 36, dim3(32, 8), 0, stream>>>(W1, Wt, 6, 1152, 1152);
    cast_x_kernel<<<(NX + 255) / 256, 256, 0, stream>>>(x, T[0], NX);
    prop1152(T[0], NB, T[1]);
    prop1152(T[1], T[0], T[2]);
    prop1152(T[2], T[1], T[3]);
    prop1152(T[3], T[2], T[4]);
    prop1152(T[4], T[3], T[5]);
    {
      APtrs a = {{T[0], T[1], T[2], T[3], T[4], T[5]}};
      gemm_kernel<4, 6><<<GMT * 9, 256, 0, stream>>>(a, Wt, b1, nullptr, T[6],
                                                     N_NODES, 1152, 1152, 1152);
    }

    // layer 2: K=5, 1152 -> 576 ; h1 = T[6]
    wtrans_kernel<<<5 * 36 * 18, dim3(32, 8), 0, stream>>>(W2, Wt, 5, 1152, 576);
    prop1152(T[6], NB, T[0]);
    prop1152(T[0], T[6], T[1]);
    prop1152(T[1], T[0], T[2]);
    prop1152(T[2], T[1], T[3]);
    {
      APtrs a = {{T[6], T[0], T[1], T[2], T[3], nullptr}};
      gemm_kernel<4, 5><<<GMT * 5, 256, 0, stream>>>(a, Wt, b2, nullptr, T[4],
                                                     N_NODES, 576, 1152, 576);
    }

    // layer 3: K=5, 576 -> 288 ; h2 = T[4]
    wtrans_kernel<<<5 * 18 * 9, dim3(32, 8), 0, stream>>>(W3, Wt, 5, 576, 288);
    prop_kernel<576, 2><<<N_NODES, 320, 0, stream>>>(row_ptr, col_s, w_s, T[4], NB, T[5]);
    prop_kernel<576, 2><<<N_NODES, 320, 0, stream>>>(row_ptr, col_s, w_s, T[5], T[4], T[0]);
    prop_kernel<576, 2><<<N_NODES, 320, 0, stream>>>(row_ptr, col_s, w_s, T[0], T[5], T[1]);
    prop_kernel<576, 2><<<N_NODES, 320, 0, stream>>>(row_ptr, col_s, w_s, T[1], T[0], T[2]);
    {
      APtrs a = {{T[4], T[5], T[0], T[1], T[2], nullptr}};
      gemm_kernel<5, 5><<<GMT * 3, 256, 0, stream>>>(a, Wt, b3, nullptr, d_out,
                                                     N_NODES, 288, 576, 0);
    }
    return;
  }

  // ================= Tiers B/C: rolling buffers + fp32 accbuf =================
  bf16* TxP = (bf16*)alloc(TXB);
  bf16* TxQ = (bf16*)alloc(TXB);
  bf16* Th = (tier == 1) ? (bf16*)alloc(TXB) : nullptr;
  float* accb = (float*)alloc((size_t)N_NODES * 1152 * 4);
  if (off > ws_size) return;

  wtrans_kernel<<<6 * 36 * 36, dim3(32, 8), 0, stream>>>(W1, Wt, 6, 1152, 1152);
  cast_x_kernel<<<(NX + 255) / 256, 256, 0, stream>>>(x, TxP, NX);
  {
    const int F = 1152, NO = 1152, nb = 9;
    size_t wsl = (size_t)NO * F;
    prop1152(TxP, NB, TxQ);
    APtrs a01 = {{TxP, TxQ}};
    gemm_kernel<0, 2><<<GMT * nb, 256, 0, stream>>>(a01, Wt, b1, accb, nullptr,
                                                    N_NODES, NO, F, 0);
    prop1152(TxQ, TxP, TxP);
    prop1152(TxP, TxQ, TxQ);
    APtrs a23 = {{TxP, TxQ}};
    gemm_kernel<1, 2><<<GMT * nb, 256, 0, stream>>>(a23, Wt + 2 * wsl, b1, accb, nullptr,
                                                    N_NODES, NO, F, 0);
    prop1152(TxQ, TxP, TxP);
    prop1152(TxP, TxQ, TxQ);
    if (tier == 1) {
      APtrs a45 = {{TxP, TxQ}};
      gemm_kernel<2, 2><<<GMT * nb, 256, 0, stream>>>(a45, Wt + 4 * wsl, b1, accb, Th,
                                                      N_NODES, NO, F, 1152);
    } else {
      APtrs a4 = {{TxP}};
      gemm_kernel<1, 1><<<GMT * nb, 256, 0, stream>>>(a4, Wt + 4 * wsl, b1, accb, nullptr,
                                                      N_NODES, NO, F, 0);
      APtrs a5 = {{TxQ}};
      gemm_kernel<2, 1><<<GMT * nb, 256, 0, stream>>>(a5, Wt + 5 * wsl, b1, accb, TxP,
                                                      N_NODES, NO, F, 1152);
    }
  }

  bf16* h1 = (tier == 1) ? Th : TxP;
  bf16* u0 = (tier == 1) ? TxP : TxQ;
  bf16* u1 = (tier == 1) ? TxQ : TxP;

  wtrans_kernel<<<5 * 36 * 18, dim3(32, 8), 0, stream>>>(W2, Wt, 5, 1152, 576);
  {
    const int F = 1152, NO = 576, nb = 5;
    size_t wsl = (size_t)NO * F;
    prop1152(h1, NB, u0);
    APtrs a01 = {{h1, u0}};
    gemm_kernel<0, 2><<<GMT * nb, 256, 0, stream>>>(a01, Wt, b2, accb, nullptr,
                                                    N_NODES, NO, F, 0);
    prop1152(u0, h1, h1);
    prop1152(h1, u0, u0);
    APtrs a23 = {{h1, u0}};
    gemm_kernel<1, 2><<<GMT * nb, 256, 0, stream>>>(a23, Wt + 2 * wsl, b2, accb, nullptr,
                                                    N_NODES, NO, F, 0);
    prop1152(u0, h1, h1);
    APtrs a4 = {{h1}};
    gemm_kernel<2, 1><<<GMT * nb, 256, 0, stream>>>(a4, Wt + 4 * wsl, b2, accb, u0,
                                                    N_NODES, NO, F, 576);
  }

  bf16* h2 = u0;

  wtrans_kernel<<<5 * 18 * 9, dim3(32, 8), 0, stream>>>(W3, Wt, 5, 576, 288);
  {
    const int F = 576, NO = 288, nb = 3;
    size_t wsl = (size_t)NO * F;
    prop_kernel<576, 2><<<N_NODES, 320, 0, stream>>>(row_ptr, col_s, w_s, h2, NB, u1);
    APtrs a01 = {{h2, u1}};
    gemm_kernel<0, 2><<<GMT * nb, 256, 0, stream>>>(a01, Wt, b3, accb, nullptr,
                                                    N_NODES, NO, F, 0);
    prop_kernel<576, 2><<<N_NODES, 320, 0, stream>>>(row_ptr, col_s, w_s, u1, h2, h2);
    prop_kernel<576, 2><<<N_NODES, 320, 0, stream>>>(row_ptr, col_s, w_s, h2, u1, u1);
    APtrs a23 = {{h2, u1}};
    gemm_kernel<1, 2><<<GMT * nb, 256, 0, stream>>>(a23, Wt + 2 * wsl, b3, accb, nullptr,
                                                    N_NODES, NO, F, 0);
    prop_kernel<576, 2><<<N_NODES, 320, 0, stream>>>(row_ptr, col_s, w_s, u1, h2, h2);
    APtrs a4 = {{h2}};
    gemm_kernel<3, 1><<<GMT * nb, 256, 0, stream>>>(a4, Wt + 4 * wsl, b3, accb, d_out,
                                                    N_NODES, NO, F, 0);
  }
}

// Round 8
// 2170.315 us; speedup vs baseline: 1.2713x; 1.2713x over previous
//
#include <hip/hip_runtime.h>
#include <hip/hip_bf16.h>

#define N_NODES 20000
#define N_EDGES 320000

typedef __attribute__((ext_vector_type(8))) short shortx8;
typedef __attribute__((ext_vector_type(4))) float floatx4;
using bf16 = __hip_bfloat16;

typedef __attribute__((address_space(1))) const unsigned int GuT;
typedef __attribute__((address_space(3))) unsigned int LuT;
__device__ __forceinline__ void gl2lds16(const bf16* g, bf16* l) {
  __builtin_amdgcn_global_load_lds((GuT*)g, (LuT*)l, 16, 0, 0);
}

__device__ inline float b2f(unsigned short u) {
  union { unsigned int i; float f; } x;
  x.i = ((unsigned int)u) << 16;
  return x.f;
}
__device__ inline unsigned short f2b(float f) {
  bf16 h(f);
  return *(unsigned short*)&h;
}

struct APtrs { const bf16* p[6]; };

// ---------------- graph prep ----------------

__global__ void zero_kernel(int* p, int n) {
  int i = blockIdx.x * 256 + threadIdx.x;
  if (i < n) p[i] = 0;
}

__global__ void deg_kernel(const int* __restrict__ row, const int* __restrict__ col,
                           int* __restrict__ deg, int nE) {
  int e = blockIdx.x * 256 + threadIdx.x;
  if (e >= nE) return;
  int r = row[e], c = col[e];
  if (r != c) atomicAdd(&deg[r], 1);
}

__global__ void dis_kernel(const int* __restrict__ deg, float* __restrict__ dis, int n) {
  int i = blockIdx.x * 256 + threadIdx.x;
  if (i >= n) return;
  int d = deg[i];
  dis[i] = (d > 0) ? (1.0f / sqrtf((float)d)) : 0.0f;
}

__global__ __launch_bounds__(1024) void scan_kernel(const int* __restrict__ deg,
                                                    int* __restrict__ row_ptr,
                                                    int* __restrict__ cursor, int n) {
  __shared__ int part[1024];
  int t = threadIdx.x;
  int base = t * 20;
  int loc[20];
  int s = 0;
#pragma unroll
  for (int i = 0; i < 20; i++) {
    int idx = base + i;
    int v = (idx < n) ? deg[idx] : 0;
    loc[i] = s;
    s += v;
  }
  part[t] = s;
  __syncthreads();
  for (int offd = 1; offd < 1024; offd <<= 1) {
    int v = (t >= offd) ? part[t - offd] : 0;
    __syncthreads();
    part[t] += v;
    __syncthreads();
  }
  int basev = (t > 0) ? part[t - 1] : 0;
#pragma unroll
  for (int i = 0; i < 20; i++) {
    int idx = base + i;
    if (idx < n) {
      int rp = basev + loc[i];
      row_ptr[idx] = rp;
      cursor[idx] = rp;
    }
  }
  if (t == 1023) row_ptr[n] = part[1023];
}

__global__ void scatter_kernel(const int* __restrict__ row, const int* __restrict__ col,
                               const float* __restrict__ dis, int* __restrict__ cursor,
                               int* __restrict__ col_s, float* __restrict__ w_s, int nE) {
  int e = blockIdx.x * 256 + threadIdx.x;
  if (e >= nE) return;
  int r = row[e], c = col[e];
  if (r == c) return;
  int p = atomicAdd(&cursor[r], 1);
  col_s[p] = c;
  w_s[p] = -dis[r] * dis[c];
}

// ---------------- weight prep: W (K,I,J) fp32 -> Wt[k][j][i] bf16 ----------------

__global__ void wtrans_kernel(const float* __restrict__ W, bf16* __restrict__ Wt,
                              int K_, int I, int J) {
  __shared__ float tile[32][33];
  int jt = blockIdx.x % (J / 32);
  int rest = blockIdx.x / (J / 32);
  int it = rest % (I / 32);
  int k = rest / (I / 32);
  int tx = threadIdx.x, ty = threadIdx.y;
  const float* src = W + (size_t)k * I * J;
  for (int r = ty; r < 32; r += 8)
    tile[r][tx] = src[(size_t)(it * 32 + r) * J + jt * 32 + tx];
  __syncthreads();
  for (int r = ty; r < 32; r += 8) {
    int j = jt * 32 + r;
    Wt[((size_t)k * J + j) * I + it * 32 + tx] = bf16(tile[tx][r]);
  }
}

// ---------------- cast x (fp32 flat) -> bf16 ----------------

__global__ void cast_x_kernel(const float* __restrict__ x, bf16* __restrict__ dst, int n4) {
  int idx = blockIdx.x * 256 + threadIdx.x;
  if (idx >= n4) return;
  int flat = idx * 4;
  float4 v = *(const float4*)(x + flat);
  dst[flat + 0] = bf16(v.x);
  dst[flat + 1] = bf16(v.y);
  dst[flat + 2] = bf16(v.z);
  dst[flat + 3] = bf16(v.w);
}

// ---------------- prop: dst = L~ src, or dst = 2*L~ src - tx0 (tx0 may alias dst) ----
// Round-6 structure (one block per node, whole row per edge), upgraded to
// 16B/lane gathers: BLK=192 threads, 144 active, VEC=8 (F=1152) / VEC=4 (F=576).
// 8-edge unroll for memory-level parallelism.

template <int F, int VEC, int BLK>
__global__ __launch_bounds__(BLK) void prop_kernel(
    const int* __restrict__ row_ptr, const int* __restrict__ col_s,
    const float* __restrict__ w_s, const bf16* __restrict__ src,
    const bf16* tx0, bf16* dst) {
  constexpr int C = F / VEC;  // 144
  int node = blockIdx.x;
  int t = threadIdx.x;
  bool act = t < C;
  int fb = t * VEC;
  int e0 = row_ptr[node], e1 = row_ptr[node + 1];
  float acc[VEC];
#pragma unroll
  for (int q = 0; q < VEC; q++) acc[q] = 0.0f;

  const unsigned short* sp = (const unsigned short*)src;
  int e = e0;
  for (; e + 8 <= e1; e += 8) {
    int cs[8];
    float wv[8];
#pragma unroll
    for (int u = 0; u < 8; u++) {
      cs[u] = col_s[e + u];
      wv[u] = w_s[e + u];
    }
    if (act) {
      if constexpr (VEC == 8) {
        shortx8 v[8];
#pragma unroll
        for (int u = 0; u < 8; u++) v[u] = *(const shortx8*)(sp + (size_t)cs[u] * F + fb);
#pragma unroll
        for (int u = 0; u < 8; u++)
#pragma unroll
          for (int q = 0; q < 8; q++) acc[q] += wv[u] * b2f((unsigned short)v[u][q]);
      } else {
        ushort4 v[8];
#pragma unroll
        for (int u = 0; u < 8; u++) v[u] = *(const ushort4*)(sp + (size_t)cs[u] * F + fb);
#pragma unroll
        for (int u = 0; u < 8; u++) {
          acc[0] += wv[u] * b2f(v[u].x);
          acc[1] += wv[u] * b2f(v[u].y);
          acc[2] += wv[u] * b2f(v[u].z);
          acc[3] += wv[u] * b2f(v[u].w);
        }
      }
    }
  }
  for (; e < e1; e++) {
    int c = col_s[e];
    float w = w_s[e];
    if (act) {
      if constexpr (VEC == 8) {
        shortx8 v = *(const shortx8*)(sp + (size_t)c * F + fb);
#pragma unroll
        for (int q = 0; q < 8; q++) acc[q] += w * b2f((unsigned short)v[q]);
      } else {
        ushort4 v = *(const ushort4*)(sp + (size_t)c * F + fb);
        acc[0] += w * b2f(v.x);
        acc[1] += w * b2f(v.y);
        acc[2] += w * b2f(v.z);
        acc[3] += w * b2f(v.w);
      }
    }
  }

  if (!act) return;
  unsigned short* dp = (unsigned short*)dst + (size_t)node * F + fb;
  if (tx0) {
    const unsigned short* t0 = (const unsigned short*)tx0 + (size_t)node * F + fb;
    if constexpr (VEC == 8) {
      shortx8 tv = *(const shortx8*)t0;
      shortx8 o;
#pragma unroll
      for (int q = 0; q < 8; q++)
        o[q] = (short)f2b(2.0f * acc[q] - b2f((unsigned short)tv[q]));
      *(shortx8*)dp = o;
    } else {
      ushort4 tv = *(const ushort4*)t0;
      ushort4 o;
      o.x = f2b(2.0f * acc[0] - b2f(tv.x));
      o.y = f2b(2.0f * acc[1] - b2f(tv.y));
      o.z = f2b(2.0f * acc[2] - b2f(tv.z));
      o.w = f2b(2.0f * acc[3] - b2f(tv.w));
      *(ushort4*)dp = o;
    }
  } else {
    if constexpr (VEC == 8) {
      shortx8 o;
#pragma unroll
      for (int q = 0; q < 8; q++) o[q] = (short)f2b(acc[q]);
      *(shortx8*)dp = o;
    } else {
      ushort4 o;
      o.x = f2b(acc[0]);
      o.y = f2b(acc[1]);
      o.z = f2b(acc[2]);
      o.w = f2b(acc[3]);
      *(ushort4*)dp = o;
    }
  }
}

// ---------------- bf16 MFMA GEMM (m97 structure), multi-segment, XCD-swizzled ------

template <int MODE, int NSEG>
__global__ __launch_bounds__(256) void gemm_kernel(
    APtrs ap, const bf16* __restrict__ Bbase,
    const float* __restrict__ bias, float* __restrict__ accbuf,
    void* __restrict__ dst, int M, int Nout, int Kt, int dstLd) {
  __shared__ bf16 As[128 * 32];
  __shared__ bf16 Bs[128 * 32];
  int nb = (Nout + 127) >> 7;
  int mtiles = (M + 127) >> 7;
  int xcd = blockIdx.x & 7;
  int s = blockIdx.x >> 3;
  int bn = s % nb;
  int bm = (s / nb) * 8 + xcd;
  if (bm >= mtiles) return;
  int m0 = bm << 7, n0 = bn << 7;
  int t = threadIdx.x;
  int lane = t & 63;
  int wave = t >> 6;
  int wm = wave & 1, wn = wave >> 1;
  int l16 = lane & 15;
  int k8 = (lane >> 4) << 3;
  floatx4 acc[4][4] = {};

  int srow = lane >> 2;
  int scol = (lane & 3) << 3;

#pragma unroll
  for (int seg = 0; seg < NSEG; seg++) {
    const bf16* A = ap.p[seg];
    const bf16* Bt = Bbase + (size_t)seg * Nout * Kt;
#pragma unroll 1
    for (int kt = 0; kt < Kt; kt += 32) {
#pragma unroll
      for (int q = 0; q < 2; q++) {
        int inst = (wave << 1) + q;
        int r = (inst << 4) + srow;
        int ga = m0 + r;
        if (ga < M)
          gl2lds16(A + (size_t)ga * Kt + kt + scol, &As[inst << 9]);
        int gb = n0 + r;
        if (gb < Nout)
          gl2lds16(Bt + (size_t)gb * Kt + kt + scol, &Bs[inst << 9]);
      }
      __syncthreads();
      shortx8 af[4], bfr[4];
#pragma unroll
      for (int i = 0; i < 4; i++)
        af[i] = *(const shortx8*)&As[(((wm << 6) + (i << 4) + l16) << 5) + k8];
#pragma unroll
      for (int j = 0; j < 4; j++)
        bfr[j] = *(const shortx8*)&Bs[(((wn << 6) + (j << 4) + l16) << 5) + k8];
#pragma unroll
      for (int i = 0; i < 4; i++)
#pragma unroll
        for (int j = 0; j < 4; j++)
          acc[i][j] = __builtin_amdgcn_mfma_f32_16x16x32_bf16(af[i], bfr[j], acc[i][j], 0, 0, 0);
      __syncthreads();
    }
  }

  int lq = lane >> 4;
#pragma unroll
  for (int j = 0; j < 4; j++) {
    int colg = n0 + (wn << 6) + (j << 4) + l16;
    if (colg >= Nout) continue;
    float bv = (MODE == 0 || MODE == 4 || MODE == 5) ? bias[colg] : 0.0f;
#pragma unroll
    for (int i = 0; i < 4; i++) {
      int rowb = m0 + (wm << 6) + (i << 4) + (lq << 2);
#pragma unroll
      for (int q = 0; q < 4; q++) {
        int rowg = rowb + q;
        if (rowg >= M) continue;
        float v = acc[i][j][q];
        size_t aidx = (size_t)rowg * Nout + colg;
        if constexpr (MODE == 0) {
          accbuf[aidx] = v + bv;
        } else if constexpr (MODE == 1) {
          accbuf[aidx] += v;
        } else if constexpr (MODE == 2) {
          float s2 = fmaxf(accbuf[aidx] + v, 0.0f);
          ((bf16*)dst)[(size_t)rowg * dstLd + colg] = bf16(s2);
        } else if constexpr (MODE == 3) {
          float s2 = fmaxf(accbuf[aidx] + v, 0.0f);
          ((float*)dst)[(size_t)rowg * Nout + colg] = s2;
        } else if constexpr (MODE == 4) {
          float s2 = fmaxf(v + bv, 0.0f);
          ((bf16*)dst)[(size_t)rowg * dstLd + colg] = bf16(s2);
        } else {
          float s2 = fmaxf(v + bv, 0.0f);
          ((float*)dst)[(size_t)rowg * Nout + colg] = s2;
        }
      }
    }
  }
}

// ---------------- host launch ----------------

extern "C" void kernel_launch(void* const* d_in, const int* in_sizes, int n_in,
                              void* d_out, int out_size, void* d_ws, size_t ws_size,
                              hipStream_t stream) {
  const float* x = (const float*)d_in[0];
  const int* row = (const int*)d_in[1];
  const int* col = (const int*)d_in[2];
  const float* W1 = (const float*)d_in[3];
  const float* b1 = (const float*)d_in[4];
  const float* W2 = (const float*)d_in[5];
  const float* b2 = (const float*)d_in[6];
  const float* W3 = (const float*)d_in[7];
  const float* b3 = (const float*)d_in[8];

  char* ws = (char*)d_ws;
  size_t off = 0;
  auto alloc = [&](size_t bytes) -> void* {
    void* p = ws + off;
    off += (bytes + 255) & ~(size_t)255;
    return p;
  };

  const size_t TXB = (size_t)N_NODES * 1152 * 2;
  bf16* Wt = (bf16*)alloc((size_t)6 * 1152 * 1152 * 2);
  int* deg = (int*)alloc(N_NODES * 4);
  float* dis = (float*)alloc(N_NODES * 4);
  int* row_ptr = (int*)alloc((N_NODES + 1) * 4);
  int* cursor = (int*)alloc(N_NODES * 4);
  int* col_s = (int*)alloc(N_EDGES * 4);
  float* w_s = (float*)alloc(N_EDGES * 4);
  size_t off_common = off;

  size_t need_A = off_common + 7 * ((TXB + 255) & ~(size_t)255);
  size_t need_B = off_common + 3 * ((TXB + 255) & ~(size_t)255) +
                  (((size_t)N_NODES * 1152 * 4 + 255) & ~(size_t)255);
  int tier = (ws_size >= need_A) ? 0 : (ws_size >= need_B) ? 1 : 2;

  zero_kernel<<<(N_NODES + 255) / 256, 256, 0, stream>>>(deg, N_NODES);
  deg_kernel<<<(N_EDGES + 255) / 256, 256, 0, stream>>>(row, col, deg, N_EDGES);
  dis_kernel<<<(N_NODES + 255) / 256, 256, 0, stream>>>(deg, dis, N_NODES);
  scan_kernel<<<1, 1024, 0, stream>>>(deg, row_ptr, cursor, N_NODES);
  scatter_kernel<<<(N_EDGES + 255) / 256, 256, 0, stream>>>(row, col, dis, cursor,
                                                            col_s, w_s, N_EDGES);

  const int MT = (N_NODES + 127) >> 7;
  const int GMT = 8 * ((MT + 7) >> 3);  // 160
  const bf16* NB = nullptr;
  const int NX = N_NODES * 1152 / 4;

  auto prop1152 = [&](const bf16* src, const bf16* tx0, bf16* dst) {
    prop_kernel<1152, 8, 192><<<N_NODES, 192, 0, stream>>>(row_ptr, col_s, w_s, src,
                                                           tx0, dst);
  };
  auto prop576 = [&](const bf16* src, const bf16* tx0, bf16* dst) {
    prop_kernel<576, 4, 192><<<N_NODES, 192, 0, stream>>>(row_ptr, col_s, w_s, src,
                                                          tx0, dst);
  };

  if (tier == 0) {
    // ================= Tier A: batched-K, no accumulator =================
    bf16* T[7];
    for (int i = 0; i < 7; i++) T[i] = (bf16*)alloc(TXB);

    // layer 1: K=6, 1152 -> 1152
    wtrans_kernel<<<6 * 36 * 36, dim3(32, 8), 0, stream>>>(W1, Wt, 6, 1152, 1152);
    cast_x_kernel<<<(NX + 255) / 256, 256, 0, stream>>>(x, T[0], NX);
    prop1152(T[0], NB, T[1]);
    prop1152(T[1], T[0], T[2]);
    prop1152(T[2], T[1], T[3]);
    prop1152(T[3], T[2], T[4]);
    prop1152(T[4], T[3], T[5]);
    {
      APtrs a = {{T[0], T[1], T[2], T[3], T[4], T[5]}};
      gemm_kernel<4, 6><<<GMT * 9, 256, 0, stream>>>(a, Wt, b1, nullptr, T[6],
                                                     N_NODES, 1152, 1152, 1152);
    }

    // layer 2: K=5, 1152 -> 576 ; h1 = T[6]
    wtrans_kernel<<<5 * 36 * 18, dim3(32, 8), 0, stream>>>(W2, Wt, 5, 1152, 576);
    prop1152(T[6], NB, T[0]);
    prop1152(T[0], T[6], T[1]);
    prop1152(T[1], T[0], T[2]);
    prop1152(T[2], T[1], T[3]);
    {
      APtrs a = {{T[6], T[0], T[1], T[2], T[3], nullptr}};
      gemm_kernel<4, 5><<<GMT * 5, 256, 0, stream>>>(a, Wt, b2, nullptr, T[4],
                                                     N_NODES, 576, 1152, 576);
    }

    // layer 3: K=5, 576 -> 288 ; h2 = T[4]
    wtrans_kernel<<<5 * 18 * 9, dim3(32, 8), 0, stream>>>(W3, Wt, 5, 576, 288);
    prop576(T[4], NB, T[5]);
    prop576(T[5], T[4], T[0]);
    prop576(T[0], T[5], T[1]);
    prop576(T[1], T[0], T[2]);
    {
      APtrs a = {{T[4], T[5], T[0], T[1], T[2], nullptr}};
      gemm_kernel<5, 5><<<GMT * 3, 256, 0, stream>>>(a, Wt, b3, nullptr, d_out,
                                                     N_NODES, 288, 576, 0);
    }
    return;
  }

  // ================= Tiers B/C: rolling buffers + fp32 accbuf =================
  bf16* TxP = (bf16*)alloc(TXB);
  bf16* TxQ = (bf16*)alloc(TXB);
  bf16* Th = (tier == 1) ? (bf16*)alloc(TXB) : nullptr;
  float* accb = (float*)alloc((size_t)N_NODES * 1152 * 4);
  if (off > ws_size) return;

  wtrans_kernel<<<6 * 36 * 36, dim3(32, 8), 0, stream>>>(W1, Wt, 6, 1152, 1152);
  cast_x_kernel<<<(NX + 255) / 256, 256, 0, stream>>>(x, TxP, NX);
  {
    const int F = 1152, NO = 1152, nb = 9;
    size_t wsl = (size_t)NO * F;
    prop1152(TxP, NB, TxQ);
    APtrs a01 = {{TxP, TxQ}};
    gemm_kernel<0, 2><<<GMT * nb, 256, 0, stream>>>(a01, Wt, b1, accb, nullptr,
                                                    N_NODES, NO, F, 0);
    prop1152(TxQ, TxP, TxP);
    prop1152(TxP, TxQ, TxQ);
    APtrs a23 = {{TxP, TxQ}};
    gemm_kernel<1, 2><<<GMT * nb, 256, 0, stream>>>(a23, Wt + 2 * wsl, b1, accb, nullptr,
                                                    N_NODES, NO, F, 0);
    prop1152(TxQ, TxP, TxP);
    prop1152(TxP, TxQ, TxQ);
    if (tier == 1) {
      APtrs a45 = {{TxP, TxQ}};
      gemm_kernel<2, 2><<<GMT * nb, 256, 0, stream>>>(a45, Wt + 4 * wsl, b1, accb, Th,
                                                      N_NODES, NO, F, 1152);
    } else {
      APtrs a4 = {{TxP}};
      gemm_kernel<1, 1><<<GMT * nb, 256, 0, stream>>>(a4, Wt + 4 * wsl, b1, accb, nullptr,
                                                      N_NODES, NO, F, 0);
      APtrs a5 = {{TxQ}};
      gemm_kernel<2, 1><<<GMT * nb, 256, 0, stream>>>(a5, Wt + 5 * wsl, b1, accb, TxP,
                                                      N_NODES, NO, F, 1152);
    }
  }

  bf16* h1 = (tier == 1) ? Th : TxP;
  bf16* u0 = (tier == 1) ? TxP : TxQ;
  bf16* u1 = (tier == 1) ? TxQ : TxP;

  wtrans_kernel<<<5 * 36 * 18, dim3(32, 8), 0, stream>>>(W2, Wt, 5, 1152, 576);
  {
    const int F = 1152, NO = 576, nb = 5;
    size_t wsl = (size_t)NO * F;
    prop1152(h1, NB, u0);
    APtrs a01 = {{h1, u0}};
    gemm_kernel<0, 2><<<GMT * nb, 256, 0, stream>>>(a01, Wt, b2, accb, nullptr,
                                                    N_NODES, NO, F, 0);
    prop1152(u0, h1, h1);
    prop1152(h1, u0, u0);
    APtrs a23 = {{h1, u0}};
    gemm_kernel<1, 2><<<GMT * nb, 256, 0, stream>>>(a23, Wt + 2 * wsl, b2, accb, nullptr,
                                                    N_NODES, NO, F, 0);
    prop1152(u0, h1, h1);
    APtrs a4 = {{h1}};
    gemm_kernel<2, 1><<<GMT * nb, 256, 0, stream>>>(a4, Wt + 4 * wsl, b2, accb, u0,
                                                    N_NODES, NO, F, 576);
  }

  bf16* h2 = u0;

  wtrans_kernel<<<5 * 18 * 9, dim3(32, 8), 0, stream>>>(W3, Wt, 5, 576, 288);
  {
    const int F = 576, NO = 288, nb = 3;
    size_t wsl = (size_t)NO * F;
    prop576(h2, NB, u1);
    APtrs a01 = {{h2, u1}};
    gemm_kernel<0, 2><<<GMT * nb, 256, 0, stream>>>(a01, Wt, b3, accb, nullptr,
                                                    N_NODES, NO, F, 0);
    prop576(u1, h2, h2);
    prop576(h2, u1, u1);
    APtrs a23 = {{h2, u1}};
    gemm_kernel<1, 2><<<GMT * nb, 256, 0, stream>>>(a23, Wt + 2 * wsl, b3, accb, nullptr,
                                                    N_NODES, NO, F, 0);
    prop576(u1, h2, h2);
    APtrs a4 = {{h2}};
    gemm_kernel<3, 1><<<GMT * nb, 256, 0, stream>>>(a4, Wt + 4 * wsl, b3, accb, d_out,
                                                    N_NODES, NO, F, 0);
  }
}

// Round 9
// 2120.383 us; speedup vs baseline: 1.3013x; 1.0235x over previous
//
#include <hip/hip_runtime.h>
#include <hip/hip_bf16.h>

#define N_NODES 20000
#define N_EDGES 320000

typedef __attribute__((ext_vector_type(8))) short shortx8;
typedef __attribute__((ext_vector_type(4))) float floatx4;
using bf16 = __hip_bfloat16;

typedef __attribute__((address_space(1))) const unsigned int GuT;
typedef __attribute__((address_space(3))) unsigned int LuT;
__device__ __forceinline__ void gl2lds16(const bf16* g, bf16* l) {
  __builtin_amdgcn_global_load_lds((GuT*)g, (LuT*)l, 16, 0, 0);
}

__device__ inline float b2f(unsigned short u) {
  union { unsigned int i; float f; } x;
  x.i = ((unsigned int)u) << 16;
  return x.f;
}
__device__ inline unsigned short f2b(float f) {
  bf16 h(f);
  return *(unsigned short*)&h;
}

struct APtrs { const bf16* p[6]; };

// ---------------- graph prep ----------------

__global__ void zero_kernel(int* p, int n) {
  int i = blockIdx.x * 256 + threadIdx.x;
  if (i < n) p[i] = 0;
}

__global__ void deg_kernel(const int* __restrict__ row, const int* __restrict__ col,
                           int* __restrict__ deg, int nE) {
  int e = blockIdx.x * 256 + threadIdx.x;
  if (e >= nE) return;
  int r = row[e], c = col[e];
  if (r != c) atomicAdd(&deg[r], 1);
}

__global__ void dis_kernel(const int* __restrict__ deg, float* __restrict__ dis, int n) {
  int i = blockIdx.x * 256 + threadIdx.x;
  if (i >= n) return;
  int d = deg[i];
  dis[i] = (d > 0) ? (1.0f / sqrtf((float)d)) : 0.0f;
}

__global__ __launch_bounds__(1024) void scan_kernel(const int* __restrict__ deg,
                                                    int* __restrict__ row_ptr,
                                                    int* __restrict__ cursor, int n) {
  __shared__ int part[1024];
  int t = threadIdx.x;
  int base = t * 20;
  int loc[20];
  int s = 0;
#pragma unroll
  for (int i = 0; i < 20; i++) {
    int idx = base + i;
    int v = (idx < n) ? deg[idx] : 0;
    loc[i] = s;
    s += v;
  }
  part[t] = s;
  __syncthreads();
  for (int offd = 1; offd < 1024; offd <<= 1) {
    int v = (t >= offd) ? part[t - offd] : 0;
    __syncthreads();
    part[t] += v;
    __syncthreads();
  }
  int basev = (t > 0) ? part[t - 1] : 0;
#pragma unroll
  for (int i = 0; i < 20; i++) {
    int idx = base + i;
    if (idx < n) {
      int rp = basev + loc[i];
      row_ptr[idx] = rp;
      cursor[idx] = rp;
    }
  }
  if (t == 1023) row_ptr[n] = part[1023];
}

__global__ void scatter_kernel(const int* __restrict__ row, const int* __restrict__ col,
                               const float* __restrict__ dis, int* __restrict__ cursor,
                               int* __restrict__ col_s, float* __restrict__ w_s, int nE) {
  int e = blockIdx.x * 256 + threadIdx.x;
  if (e >= nE) return;
  int r = row[e], c = col[e];
  if (r == c) return;
  int p = atomicAdd(&cursor[r], 1);
  col_s[p] = c;
  w_s[p] = -dis[r] * dis[c];
}

// ---------------- weight prep: W (K,I,J) fp32 -> Wt[k][j][i] bf16 ----------------

__global__ void wtrans_kernel(const float* __restrict__ W, bf16* __restrict__ Wt,
                              int K_, int I, int J) {
  __shared__ float tile[32][33];
  int jt = blockIdx.x % (J / 32);
  int rest = blockIdx.x / (J / 32);
  int it = rest % (I / 32);
  int k = rest / (I / 32);
  int tx = threadIdx.x, ty = threadIdx.y;
  const float* src = W + (size_t)k * I * J;
  for (int r = ty; r < 32; r += 8)
    tile[r][tx] = src[(size_t)(it * 32 + r) * J + jt * 32 + tx];
  __syncthreads();
  for (int r = ty; r < 32; r += 8) {
    int j = jt * 32 + r;
    Wt[((size_t)k * J + j) * I + it * 32 + tx] = bf16(tile[tx][r]);
  }
}

// ---------------- cast x (fp32 flat) -> bf16 ----------------

__global__ void cast_x_kernel(const float* __restrict__ x, bf16* __restrict__ dst, int n4) {
  int idx = blockIdx.x * 256 + threadIdx.x;
  if (idx >= n4) return;
  int flat = idx * 4;
  float4 v = *(const float4*)(x + flat);
  dst[flat + 0] = bf16(v.x);
  dst[flat + 1] = bf16(v.y);
  dst[flat + 2] = bf16(v.z);
  dst[flat + 3] = bf16(v.w);
}

// ---------------- prop (round-6 config): one block/node, 320 thr, C=288 active ----
// VEC=4 (F=1152) / VEC=2 (F=576); 16-edge + 4-edge + scalar unroll tiers.
// tx0 may alias dst (in-place; each block owns its row).

template <int F, int VEC>
__global__ __launch_bounds__(320) void prop_kernel(
    const int* __restrict__ row_ptr, const int* __restrict__ col_s,
    const float* __restrict__ w_s, const bf16* __restrict__ src,
    const bf16* tx0, bf16* dst) {
  constexpr int C = F / VEC;  // 288
  int node = blockIdx.x;
  int t = threadIdx.x;
  bool act = t < C;
  int fb = t * VEC;
  int e0 = row_ptr[node], e1 = row_ptr[node + 1];
  float acc[VEC];
#pragma unroll
  for (int q = 0; q < VEC; q++) acc[q] = 0.0f;

  const unsigned short* sp = (const unsigned short*)src;
  int e = e0;
  for (; e + 16 <= e1; e += 16) {
    int cs[16];
    float wv[16];
#pragma unroll
    for (int u = 0; u < 16; u++) {
      cs[u] = col_s[e + u];
      wv[u] = w_s[e + u];
    }
    if (act) {
      if constexpr (VEC == 4) {
        ushort4 v[16];
#pragma unroll
        for (int u = 0; u < 16; u++) v[u] = *(const ushort4*)(sp + (size_t)cs[u] * F + fb);
#pragma unroll
        for (int u = 0; u < 16; u++) {
          acc[0] += wv[u] * b2f(v[u].x);
          acc[1] += wv[u] * b2f(v[u].y);
          acc[2] += wv[u] * b2f(v[u].z);
          acc[3] += wv[u] * b2f(v[u].w);
        }
      } else {
        ushort2 v[16];
#pragma unroll
        for (int u = 0; u < 16; u++) v[u] = *(const ushort2*)(sp + (size_t)cs[u] * F + fb);
#pragma unroll
        for (int u = 0; u < 16; u++) {
          acc[0] += wv[u] * b2f(v[u].x);
          acc[1] += wv[u] * b2f(v[u].y);
        }
      }
    }
  }
  for (; e + 4 <= e1; e += 4) {
    int cs[4];
    float wv[4];
#pragma unroll
    for (int u = 0; u < 4; u++) {
      cs[u] = col_s[e + u];
      wv[u] = w_s[e + u];
    }
    if (act) {
      if constexpr (VEC == 4) {
        ushort4 v[4];
#pragma unroll
        for (int u = 0; u < 4; u++) v[u] = *(const ushort4*)(sp + (size_t)cs[u] * F + fb);
#pragma unroll
        for (int u = 0; u < 4; u++) {
          acc[0] += wv[u] * b2f(v[u].x);
          acc[1] += wv[u] * b2f(v[u].y);
          acc[2] += wv[u] * b2f(v[u].z);
          acc[3] += wv[u] * b2f(v[u].w);
        }
      } else {
        ushort2 v[4];
#pragma unroll
        for (int u = 0; u < 4; u++) v[u] = *(const ushort2*)(sp + (size_t)cs[u] * F + fb);
#pragma unroll
        for (int u = 0; u < 4; u++) {
          acc[0] += wv[u] * b2f(v[u].x);
          acc[1] += wv[u] * b2f(v[u].y);
        }
      }
    }
  }
  for (; e < e1; e++) {
    int c = col_s[e];
    float w = w_s[e];
    if (act) {
      if constexpr (VEC == 4) {
        ushort4 v = *(const ushort4*)(sp + (size_t)c * F + fb);
        acc[0] += w * b2f(v.x);
        acc[1] += w * b2f(v.y);
        acc[2] += w * b2f(v.z);
        acc[3] += w * b2f(v.w);
      } else {
        ushort2 v = *(const ushort2*)(sp + (size_t)c * F + fb);
        acc[0] += w * b2f(v.x);
        acc[1] += w * b2f(v.y);
      }
    }
  }

  if (!act) return;
  unsigned short* dp = (unsigned short*)dst + (size_t)node * F + fb;
  if (tx0) {
    const unsigned short* t0 = (const unsigned short*)tx0 + (size_t)node * F + fb;
    if constexpr (VEC == 4) {
      ushort4 tv = *(const ushort4*)t0;
      ushort4 o;
      o.x = f2b(2.0f * acc[0] - b2f(tv.x));
      o.y = f2b(2.0f * acc[1] - b2f(tv.y));
      o.z = f2b(2.0f * acc[2] - b2f(tv.z));
      o.w = f2b(2.0f * acc[3] - b2f(tv.w));
      *(ushort4*)dp = o;
    } else {
      ushort2 tv = *(const ushort2*)t0;
      ushort2 o;
      o.x = f2b(2.0f * acc[0] - b2f(tv.x));
      o.y = f2b(2.0f * acc[1] - b2f(tv.y));
      *(ushort2*)dp = o;
    }
  } else {
    if constexpr (VEC == 4) {
      ushort4 o;
      o.x = f2b(acc[0]);
      o.y = f2b(acc[1]);
      o.z = f2b(acc[2]);
      o.w = f2b(acc[3]);
      *(ushort4*)dp = o;
    } else {
      ushort2 o;
      o.x = f2b(acc[0]);
      o.y = f2b(acc[1]);
      *(ushort2*)dp = o;
    }
  }
}

// ---------------- bf16 MFMA GEMM, multi-segment, XCD-swizzled, LDS-XOR-swizzled ----
// Staging lane L (srow=L>>2, c=L&3) fetches global 16B-chunk c^((srow>>1)&3), so
// LDS[row][c] holds global chunk c^((row>>1)&3). Fragment reads chunk
// q^((row>>1)&3) -> per-quad bank groups spread 2-way (free) instead of 8-way.

template <int MODE, int NSEG>
__global__ __launch_bounds__(256) void gemm_kernel(
    APtrs ap, const bf16* __restrict__ Bbase,
    const float* __restrict__ bias, float* __restrict__ accbuf,
    void* __restrict__ dst, int M, int Nout, int Kt, int dstLd) {
  __shared__ bf16 As[128 * 32];
  __shared__ bf16 Bs[128 * 32];
  int nb = (Nout + 127) >> 7;
  int mtiles = (M + 127) >> 7;
  int xcd = blockIdx.x & 7;
  int s = blockIdx.x >> 3;
  int bn = s % nb;
  int bm = (s / nb) * 8 + xcd;
  if (bm >= mtiles) return;
  int m0 = bm << 7, n0 = bn << 7;
  int t = threadIdx.x;
  int lane = t & 63;
  int wave = t >> 6;
  int wm = wave & 1, wn = wave >> 1;
  int l16 = lane & 15;
  int q4 = lane >> 4;  // fragment chunk 0..3
  floatx4 acc[4][4] = {};

  int srow = lane >> 2;                              // 0..15 within staging inst
  int scol = (((lane & 3) ^ ((srow >> 1) & 3)) << 3);  // swizzled global chunk

#pragma unroll
  for (int seg = 0; seg < NSEG; seg++) {
    const bf16* A = ap.p[seg];
    const bf16* Bt = Bbase + (size_t)seg * Nout * Kt;
#pragma unroll 1
    for (int kt = 0; kt < Kt; kt += 32) {
#pragma unroll
      for (int q = 0; q < 2; q++) {
        int inst = (wave << 1) + q;
        int r = (inst << 4) + srow;
        int ga = m0 + r;
        if (ga < M)
          gl2lds16(A + (size_t)ga * Kt + kt + scol, &As[inst << 9]);
        int gb = n0 + r;
        if (gb < Nout)
          gl2lds16(Bt + (size_t)gb * Kt + kt + scol, &Bs[inst << 9]);
      }
      __syncthreads();
      shortx8 af[4], bfr[4];
#pragma unroll
      for (int i = 0; i < 4; i++) {
        int r = (wm << 6) + (i << 4) + l16;
        af[i] = *(const shortx8*)&As[(r << 5) + ((q4 ^ ((r >> 1) & 3)) << 3)];
      }
#pragma unroll
      for (int j = 0; j < 4; j++) {
        int r = (wn << 6) + (j << 4) + l16;
        bfr[j] = *(const shortx8*)&Bs[(r << 5) + ((q4 ^ ((r >> 1) & 3)) << 3)];
      }
#pragma unroll
      for (int i = 0; i < 4; i++)
#pragma unroll
        for (int j = 0; j < 4; j++)
          acc[i][j] = __builtin_amdgcn_mfma_f32_16x16x32_bf16(af[i], bfr[j], acc[i][j], 0, 0, 0);
      __syncthreads();
    }
  }

  int lq = lane >> 4;
#pragma unroll
  for (int j = 0; j < 4; j++) {
    int colg = n0 + (wn << 6) + (j << 4) + l16;
    if (colg >= Nout) continue;
    float bv = (MODE == 0 || MODE == 4 || MODE == 5) ? bias[colg] : 0.0f;
#pragma unroll
    for (int i = 0; i < 4; i++) {
      int rowb = m0 + (wm << 6) + (i << 4) + (lq << 2);
#pragma unroll
      for (int q = 0; q < 4; q++) {
        int rowg = rowb + q;
        if (rowg >= M) continue;
        float v = acc[i][j][q];
        size_t aidx = (size_t)rowg * Nout + colg;
        if constexpr (MODE == 0) {
          accbuf[aidx] = v + bv;
        } else if constexpr (MODE == 1) {
          accbuf[aidx] += v;
        } else if constexpr (MODE == 2) {
          float s2 = fmaxf(accbuf[aidx] + v, 0.0f);
          ((bf16*)dst)[(size_t)rowg * dstLd + colg] = bf16(s2);
        } else if constexpr (MODE == 3) {
          float s2 = fmaxf(accbuf[aidx] + v, 0.0f);
          ((float*)dst)[(size_t)rowg * Nout + colg] = s2;
        } else if constexpr (MODE == 4) {
          float s2 = fmaxf(v + bv, 0.0f);
          ((bf16*)dst)[(size_t)rowg * dstLd + colg] = bf16(s2);
        } else {
          float s2 = fmaxf(v + bv, 0.0f);
          ((float*)dst)[(size_t)rowg * Nout + colg] = s2;
        }
      }
    }
  }
}

// ---------------- host launch ----------------

extern "C" void kernel_launch(void* const* d_in, const int* in_sizes, int n_in,
                              void* d_out, int out_size, void* d_ws, size_t ws_size,
                              hipStream_t stream) {
  const float* x = (const float*)d_in[0];
  const int* row = (const int*)d_in[1];
  const int* col = (const int*)d_in[2];
  const float* W1 = (const float*)d_in[3];
  const float* b1 = (const float*)d_in[4];
  const float* W2 = (const float*)d_in[5];
  const float* b2 = (const float*)d_in[6];
  const float* W3 = (const float*)d_in[7];
  const float* b3 = (const float*)d_in[8];

  char* ws = (char*)d_ws;
  size_t off = 0;
  auto alloc = [&](size_t bytes) -> void* {
    void* p = ws + off;
    off += (bytes + 255) & ~(size_t)255;
    return p;
  };

  const size_t TXB = (size_t)N_NODES * 1152 * 2;
  bf16* Wt = (bf16*)alloc((size_t)6 * 1152 * 1152 * 2);
  int* deg = (int*)alloc(N_NODES * 4);
  float* dis = (float*)alloc(N_NODES * 4);
  int* row_ptr = (int*)alloc((N_NODES + 1) * 4);
  int* cursor = (int*)alloc(N_NODES * 4);
  int* col_s = (int*)alloc(N_EDGES * 4);
  float* w_s = (float*)alloc(N_EDGES * 4);
  size_t off_common = off;

  size_t need_A = off_common + 7 * ((TXB + 255) & ~(size_t)255);
  size_t need_B = off_common + 3 * ((TXB + 255) & ~(size_t)255) +
                  (((size_t)N_NODES * 1152 * 4 + 255) & ~(size_t)255);
  int tier = (ws_size >= need_A) ? 0 : (ws_size >= need_B) ? 1 : 2;

  zero_kernel<<<(N_NODES + 255) / 256, 256, 0, stream>>>(deg, N_NODES);
  deg_kernel<<<(N_EDGES + 255) / 256, 256, 0, stream>>>(row, col, deg, N_EDGES);
  dis_kernel<<<(N_NODES + 255) / 256, 256, 0, stream>>>(deg, dis, N_NODES);
  scan_kernel<<<1, 1024, 0, stream>>>(deg, row_ptr, cursor, N_NODES);
  scatter_kernel<<<(N_EDGES + 255) / 256, 256, 0, stream>>>(row, col, dis, cursor,
                                                            col_s, w_s, N_EDGES);

  const int MT = (N_NODES + 127) >> 7;
  const int GMT = 8 * ((MT + 7) >> 3);  // 160
  const bf16* NB = nullptr;
  const int NX = N_NODES * 1152 / 4;

  auto prop1152 = [&](const bf16* src, const bf16* tx0, bf16* dst) {
    prop_kernel<1152, 4><<<N_NODES, 320, 0, stream>>>(row_ptr, col_s, w_s, src, tx0, dst);
  };
  auto prop576 = [&](const bf16* src, const bf16* tx0, bf16* dst) {
    prop_kernel<576, 2><<<N_NODES, 320, 0, stream>>>(row_ptr, col_s, w_s, src, tx0, dst);
  };

  if (tier == 0) {
    // ================= Tier A: batched-K, no accumulator =================
    bf16* T[7];
    for (int i = 0; i < 7; i++) T[i] = (bf16*)alloc(TXB);

    // layer 1: K=6, 1152 -> 1152
    wtrans_kernel<<<6 * 36 * 36, dim3(32, 8), 0, stream>>>(W1, Wt, 6, 1152, 1152);
    cast_x_kernel<<<(NX + 255) / 256, 256, 0, stream>>>(x, T[0], NX);
    prop1152(T[0], NB, T[1]);
    prop1152(T[1], T[0], T[2]);
    prop1152(T[2], T[1], T[3]);
    prop1152(T[3], T[2], T[4]);
    prop1152(T[4], T[3], T[5]);
    {
      APtrs a = {{T[0], T[1], T[2], T[3], T[4], T[5]}};
      gemm_kernel<4, 6><<<GMT * 9, 256, 0, stream>>>(a, Wt, b1, nullptr, T[6],
                                                     N_NODES, 1152, 1152, 1152);
    }

    // layer 2: K=5, 1152 -> 576 ; h1 = T[6]
    wtrans_kernel<<<5 * 36 * 18, dim3(32, 8), 0, stream>>>(W2, Wt, 5, 1152, 576);
    prop1152(T[6], NB, T[0]);
    prop1152(T[0], T[6], T[1]);
    prop1152(T[1], T[0], T[2]);
    prop1152(T[2], T[1], T[3]);
    {
      APtrs a = {{T[6], T[0], T[1], T[2], T[3], nullptr}};
      gemm_kernel<4, 5><<<GMT * 5, 256, 0, stream>>>(a, Wt, b2, nullptr, T[4],
                                                     N_NODES, 576, 1152, 576);
    }

    // layer 3: K=5, 576 -> 288 ; h2 = T[4]
    wtrans_kernel<<<5 * 18 * 9, dim3(32, 8), 0, stream>>>(W3, Wt, 5, 576, 288);
    prop576(T[4], NB, T[5]);
    prop576(T[5], T[4], T[0]);
    prop576(T[0], T[5], T[1]);
    prop576(T[1], T[0], T[2]);
    {
      APtrs a = {{T[4], T[5], T[0], T[1], T[2], nullptr}};
      gemm_kernel<5, 5><<<GMT * 3, 256, 0, stream>>>(a, Wt, b3, nullptr, d_out,
                                                     N_NODES, 288, 576, 0);
    }
    return;
  }

  // ================= Tiers B/C: rolling buffers + fp32 accbuf =================
  bf16* TxP = (bf16*)alloc(TXB);
  bf16* TxQ = (bf16*)alloc(TXB);
  bf16* Th = (tier == 1) ? (bf16*)alloc(TXB) : nullptr;
  float* accb = (float*)alloc((size_t)N_NODES * 1152 * 4);
  if (off > ws_size) return;

  wtrans_kernel<<<6 * 36 * 36, dim3(32, 8), 0, stream>>>(W1, Wt, 6, 1152, 1152);
  cast_x_kernel<<<(NX + 255) / 256, 256, 0, stream>>>(x, TxP, NX);
  {
    const int F = 1152, NO = 1152, nb = 9;
    size_t wsl = (size_t)NO * F;
    prop1152(TxP, NB, TxQ);
    APtrs a01 = {{TxP, TxQ}};
    gemm_kernel<0, 2><<<GMT * nb, 256, 0, stream>>>(a01, Wt, b1, accb, nullptr,
                                                    N_NODES, NO, F, 0);
    prop1152(TxQ, TxP, TxP);
    prop1152(TxP, TxQ, TxQ);
    APtrs a23 = {{TxP, TxQ}};
    gemm_kernel<1, 2><<<GMT * nb, 256, 0, stream>>>(a23, Wt + 2 * wsl, b1, accb, nullptr,
                                                    N_NODES, NO, F, 0);
    prop1152(TxQ, TxP, TxP);
    prop1152(TxP, TxQ, TxQ);
    if (tier == 1) {
      APtrs a45 = {{TxP, TxQ}};
      gemm_kernel<2, 2><<<GMT * nb, 256, 0, stream>>>(a45, Wt + 4 * wsl, b1, accb, Th,
                                                      N_NODES, NO, F, 1152);
    } else {
      APtrs a4 = {{TxP}};
      gemm_kernel<1, 1><<<GMT * nb, 256, 0, stream>>>(a4, Wt + 4 * wsl, b1, accb, nullptr,
                                                      N_NODES, NO, F, 0);
      APtrs a5 = {{TxQ}};
      gemm_kernel<2, 1><<<GMT * nb, 256, 0, stream>>>(a5, Wt + 5 * wsl, b1, accb, TxP,
                                                      N_NODES, NO, F, 1152);
    }
  }

  bf16* h1 = (tier == 1) ? Th : TxP;
  bf16* u0 = (tier == 1) ? TxP : TxQ;
  bf16* u1 = (tier == 1) ? TxQ : TxP;

  wtrans_kernel<<<5 * 36 * 18, dim3(32, 8), 0, stream>>>(W2, Wt, 5, 1152, 576);
  {
    const int F = 1152, NO = 576, nb = 5;
    size_t wsl = (size_t)NO * F;
    prop1152(h1, NB, u0);
    APtrs a01 = {{h1, u0}};
    gemm_kernel<0, 2><<<GMT * nb, 256, 0, stream>>>(a01, Wt, b2, accb, nullptr,
                                                    N_NODES, NO, F, 0);
    prop1152(u0, h1, h1);
    prop1152(h1, u0, u0);
    APtrs a23 = {{h1, u0}};
    gemm_kernel<1, 2><<<GMT * nb, 256, 0, stream>>>(a23, Wt + 2 * wsl, b2, accb, nullptr,
                                                    N_NODES, NO, F, 0);
    prop1152(u0, h1, h1);
    APtrs a4 = {{h1}};
    gemm_kernel<2, 1><<<GMT * nb, 256, 0, stream>>>(a4, Wt + 4 * wsl, b2, accb, u0,
                                                    N_NODES, NO, F, 576);
  }

  bf16* h2 = u0;

  wtrans_kernel<<<5 * 18 * 9, dim3(32, 8), 0, stream>>>(W3, Wt, 5, 576, 288);
  {
    const int F = 576, NO = 288, nb = 3;
    size_t wsl = (size_t)NO * F;
    prop576(h2, NB, u1);
    APtrs a01 = {{h2, u1}};
    gemm_kernel<0, 2><<<GMT * nb, 256, 0, stream>>>(a01, Wt, b3, accb, nullptr,
                                                    N_NODES, NO, F, 0);
    prop576(u1, h2, h2);
    prop576(h2, u1, u1);
    APtrs a23 = {{h2, u1}};
    gemm_kernel<1, 2><<<GMT * nb, 256, 0, stream>>>(a23, Wt + 2 * wsl, b3, accb, nullptr,
                                                    N_NODES, NO, F, 0);
    prop576(u1, h2, h2);
    APtrs a4 = {{h2}};
    gemm_kernel<3, 1><<<GMT * nb, 256, 0, stream>>>(a4, Wt + 4 * wsl, b3, accb, d_out,
                                                    N_NODES, NO, F, 0);
  }
}

// Round 10
// 1794.047 us; speedup vs baseline: 1.5380x; 1.1819x over previous
//
#include <hip/hip_runtime.h>
#include <hip/hip_bf16.h>

#define N_NODES 20000
#define N_EDGES 320000

typedef __attribute__((ext_vector_type(8))) short shortx8;
typedef __attribute__((ext_vector_type(4))) float floatx4;
using bf16 = __hip_bfloat16;

typedef __attribute__((address_space(1))) const unsigned int GuT;
typedef __attribute__((address_space(3))) unsigned int LuT;
__device__ __forceinline__ void gl2lds16(const bf16* g, bf16* l) {
  __builtin_amdgcn_global_load_lds((GuT*)g, (LuT*)l, 16, 0, 0);
}

__device__ inline float b2f(unsigned short u) {
  union { unsigned int i; float f; } x;
  x.i = ((unsigned int)u) << 16;
  return x.f;
}
__device__ inline unsigned short f2b(float f) {
  bf16 h(f);
  return *(unsigned short*)&h;
}

struct APtrs { const bf16* p[6]; };

// ---------------- graph prep ----------------

__global__ void zero_kernel(int* p, int n) {
  int i = blockIdx.x * 256 + threadIdx.x;
  if (i < n) p[i] = 0;
}

__global__ void deg_kernel(const int* __restrict__ row, const int* __restrict__ col,
                           int* __restrict__ deg, int nE) {
  int e = blockIdx.x * 256 + threadIdx.x;
  if (e >= nE) return;
  int r = row[e], c = col[e];
  if (r != c) atomicAdd(&deg[r], 1);
}

__global__ void dis_kernel(const int* __restrict__ deg, float* __restrict__ dis, int n) {
  int i = blockIdx.x * 256 + threadIdx.x;
  if (i >= n) return;
  int d = deg[i];
  dis[i] = (d > 0) ? (1.0f / sqrtf((float)d)) : 0.0f;
}

__global__ __launch_bounds__(1024) void scan_kernel(const int* __restrict__ deg,
                                                    int* __restrict__ row_ptr,
                                                    int* __restrict__ cursor, int n) {
  __shared__ int part[1024];
  int t = threadIdx.x;
  int base = t * 20;
  int loc[20];
  int s = 0;
#pragma unroll
  for (int i = 0; i < 20; i++) {
    int idx = base + i;
    int v = (idx < n) ? deg[idx] : 0;
    loc[i] = s;
    s += v;
  }
  part[t] = s;
  __syncthreads();
  for (int offd = 1; offd < 1024; offd <<= 1) {
    int v = (t >= offd) ? part[t - offd] : 0;
    __syncthreads();
    part[t] += v;
    __syncthreads();
  }
  int basev = (t > 0) ? part[t - 1] : 0;
#pragma unroll
  for (int i = 0; i < 20; i++) {
    int idx = base + i;
    if (idx < n) {
      int rp = basev + loc[i];
      row_ptr[idx] = rp;
      cursor[idx] = rp;
    }
  }
  if (t == 1023) row_ptr[n] = part[1023];
}

__global__ void scatter_kernel(const int* __restrict__ row, const int* __restrict__ col,
                               const float* __restrict__ dis, int* __restrict__ cursor,
                               int* __restrict__ col_s, float* __restrict__ w_s, int nE) {
  int e = blockIdx.x * 256 + threadIdx.x;
  if (e >= nE) return;
  int r = row[e], c = col[e];
  if (r == c) return;
  int p = atomicAdd(&cursor[r], 1);
  col_s[p] = c;
  w_s[p] = -dis[r] * dis[c];
}

// ---------------- weight prep: W (K,I,J) fp32 -> Wt[(k*J+j)][i] bf16 ----------------

__global__ void wtrans_kernel(const float* __restrict__ W, bf16* __restrict__ Wt,
                              int K_, int I, int J) {
  __shared__ float tile[32][33];
  int jt = blockIdx.x % (J / 32);
  int rest = blockIdx.x / (J / 32);
  int it = rest % (I / 32);
  int k = rest / (I / 32);
  int tx = threadIdx.x, ty = threadIdx.y;
  const float* src = W + (size_t)k * I * J;
  for (int r = ty; r < 32; r += 8)
    tile[r][tx] = src[(size_t)(it * 32 + r) * J + jt * 32 + tx];
  __syncthreads();
  for (int r = ty; r < 32; r += 8) {
    int j = jt * 32 + r;
    Wt[((size_t)k * J + j) * I + it * 32 + tx] = bf16(tile[tx][r]);
  }
}

// ---------------- cast x (fp32 flat) -> bf16 ----------------

__global__ void cast_x_kernel(const float* __restrict__ x, bf16* __restrict__ dst, int n4) {
  int idx = blockIdx.x * 256 + threadIdx.x;
  if (idx >= n4) return;
  int flat = idx * 4;
  float4 v = *(const float4*)(x + flat);
  dst[flat + 0] = bf16(v.x);
  dst[flat + 1] = bf16(v.y);
  dst[flat + 2] = bf16(v.z);
  dst[flat + 3] = bf16(v.w);
}

// ---------------- prop (layer-1 / fallback): dst = L~ src, or 2L~src - tx0 ---------

template <int F, int VEC>
__global__ __launch_bounds__(320) void prop_kernel(
    const int* __restrict__ row_ptr, const int* __restrict__ col_s,
    const float* __restrict__ w_s, const bf16* __restrict__ src,
    const bf16* tx0, bf16* dst) {
  constexpr int C = F / VEC;  // 288
  int node = blockIdx.x;
  int t = threadIdx.x;
  bool act = t < C;
  int fb = t * VEC;
  int e0 = row_ptr[node], e1 = row_ptr[node + 1];
  float acc[VEC];
#pragma unroll
  for (int q = 0; q < VEC; q++) acc[q] = 0.0f;

  const unsigned short* sp = (const unsigned short*)src;
  int e = e0;
  for (; e + 16 <= e1; e += 16) {
    int cs[16];
    float wv[16];
#pragma unroll
    for (int u = 0; u < 16; u++) {
      cs[u] = col_s[e + u];
      wv[u] = w_s[e + u];
    }
    if (act) {
      if constexpr (VEC == 4) {
        ushort4 v[16];
#pragma unroll
        for (int u = 0; u < 16; u++) v[u] = *(const ushort4*)(sp + (size_t)cs[u] * F + fb);
#pragma unroll
        for (int u = 0; u < 16; u++) {
          acc[0] += wv[u] * b2f(v[u].x);
          acc[1] += wv[u] * b2f(v[u].y);
          acc[2] += wv[u] * b2f(v[u].z);
          acc[3] += wv[u] * b2f(v[u].w);
        }
      } else {
        ushort2 v[16];
#pragma unroll
        for (int u = 0; u < 16; u++) v[u] = *(const ushort2*)(sp + (size_t)cs[u] * F + fb);
#pragma unroll
        for (int u = 0; u < 16; u++) {
          acc[0] += wv[u] * b2f(v[u].x);
          acc[1] += wv[u] * b2f(v[u].y);
        }
      }
    }
  }
  for (; e + 4 <= e1; e += 4) {
    int cs[4];
    float wv[4];
#pragma unroll
    for (int u = 0; u < 4; u++) {
      cs[u] = col_s[e + u];
      wv[u] = w_s[e + u];
    }
    if (act) {
      if constexpr (VEC == 4) {
        ushort4 v[4];
#pragma unroll
        for (int u = 0; u < 4; u++) v[u] = *(const ushort4*)(sp + (size_t)cs[u] * F + fb);
#pragma unroll
        for (int u = 0; u < 4; u++) {
          acc[0] += wv[u] * b2f(v[u].x);
          acc[1] += wv[u] * b2f(v[u].y);
          acc[2] += wv[u] * b2f(v[u].z);
          acc[3] += wv[u] * b2f(v[u].w);
        }
      } else {
        ushort2 v[4];
#pragma unroll
        for (int u = 0; u < 4; u++) v[u] = *(const ushort2*)(sp + (size_t)cs[u] * F + fb);
#pragma unroll
        for (int u = 0; u < 4; u++) {
          acc[0] += wv[u] * b2f(v[u].x);
          acc[1] += wv[u] * b2f(v[u].y);
        }
      }
    }
  }
  for (; e < e1; e++) {
    int c = col_s[e];
    float w = w_s[e];
    if (act) {
      if constexpr (VEC == 4) {
        ushort4 v = *(const ushort4*)(sp + (size_t)c * F + fb);
        acc[0] += w * b2f(v.x);
        acc[1] += w * b2f(v.y);
        acc[2] += w * b2f(v.z);
        acc[3] += w * b2f(v.w);
      } else {
        ushort2 v = *(const ushort2*)(sp + (size_t)c * F + fb);
        acc[0] += w * b2f(v.x);
        acc[1] += w * b2f(v.y);
      }
    }
  }

  if (!act) return;
  unsigned short* dp = (unsigned short*)dst + (size_t)node * F + fb;
  if (tx0) {
    const unsigned short* t0 = (const unsigned short*)tx0 + (size_t)node * F + fb;
    if constexpr (VEC == 4) {
      ushort4 tv = *(const ushort4*)t0;
      ushort4 o;
      o.x = f2b(2.0f * acc[0] - b2f(tv.x));
      o.y = f2b(2.0f * acc[1] - b2f(tv.y));
      o.z = f2b(2.0f * acc[2] - b2f(tv.z));
      o.w = f2b(2.0f * acc[3] - b2f(tv.w));
      *(ushort4*)dp = o;
    } else {
      ushort2 tv = *(const ushort2*)t0;
      ushort2 o;
      o.x = f2b(2.0f * acc[0] - b2f(tv.x));
      o.y = f2b(2.0f * acc[1] - b2f(tv.y));
      *(ushort2*)dp = o;
    }
  } else {
    if constexpr (VEC == 4) {
      ushort4 o;
      o.x = f2b(acc[0]);
      o.y = f2b(acc[1]);
      o.z = f2b(acc[2]);
      o.w = f2b(acc[3]);
      *(ushort4*)dp = o;
    } else {
      ushort2 o;
      o.x = f2b(acc[0]);
      o.y = f2b(acc[1]);
      *(ushort2*)dp = o;
    }
  }
}

// ---------------- Clenshaw prop: dst = alpha*(L~ src) + g - sub [+bias, relu] ------
// src/g/sub rows at stride ld (slices of the fused-GEMM output); dst stride dstLd.
// OUT: 0 = bf16 plain, 1 = bf16 bias+relu, 2 = f32 bias+relu. g may alias dst
// (in-place; each block owns its row). sub nullable.

template <int F, int VEC, int BLK, int OUT>
__global__ __launch_bounds__(BLK) void cprop_kernel(
    const int* __restrict__ row_ptr, const int* __restrict__ col_s,
    const float* __restrict__ w_s, const bf16* __restrict__ src,
    const bf16* g, const bf16* sub, void* dstv, int ld, int dstLd,
    float alpha, const float* __restrict__ bias) {
  constexpr int C = F / VEC;
  int node = blockIdx.x;
  int t = threadIdx.x;
  bool act = t < C;
  int fb = t * VEC;
  int e0 = row_ptr[node], e1 = row_ptr[node + 1];
  float acc[VEC];
#pragma unroll
  for (int q = 0; q < VEC; q++) acc[q] = 0.0f;

  const unsigned short* sp = (const unsigned short*)src;
  int e = e0;
  for (; e + 16 <= e1; e += 16) {
    int cs[16];
    float wv[16];
#pragma unroll
    for (int u = 0; u < 16; u++) {
      cs[u] = col_s[e + u];
      wv[u] = w_s[e + u];
    }
    if (act) {
      ushort2 v[16];
#pragma unroll
      for (int u = 0; u < 16; u++) v[u] = *(const ushort2*)(sp + (size_t)cs[u] * ld + fb);
#pragma unroll
      for (int u = 0; u < 16; u++) {
        acc[0] += wv[u] * b2f(v[u].x);
        acc[1] += wv[u] * b2f(v[u].y);
      }
    }
  }
  for (; e + 4 <= e1; e += 4) {
    int cs[4];
    float wv[4];
#pragma unroll
    for (int u = 0; u < 4; u++) {
      cs[u] = col_s[e + u];
      wv[u] = w_s[e + u];
    }
    if (act) {
      ushort2 v[4];
#pragma unroll
      for (int u = 0; u < 4; u++) v[u] = *(const ushort2*)(sp + (size_t)cs[u] * ld + fb);
#pragma unroll
      for (int u = 0; u < 4; u++) {
        acc[0] += wv[u] * b2f(v[u].x);
        acc[1] += wv[u] * b2f(v[u].y);
      }
    }
  }
  for (; e < e1; e++) {
    int c = col_s[e];
    float w = w_s[e];
    if (act) {
      ushort2 v = *(const ushort2*)(sp + (size_t)c * ld + fb);
      acc[0] += w * b2f(v.x);
      acc[1] += w * b2f(v.y);
    }
  }

  if (!act) return;
  const unsigned short* gp = (const unsigned short*)g + (size_t)node * ld + fb;
  ushort2 gv = *(const ushort2*)gp;
  float y0 = alpha * acc[0] + b2f(gv.x);
  float y1 = alpha * acc[1] + b2f(gv.y);
  if (sub) {
    const unsigned short* su = (const unsigned short*)sub + (size_t)node * ld + fb;
    ushort2 sv = *(const ushort2*)su;
    y0 -= b2f(sv.x);
    y1 -= b2f(sv.y);
  }
  if constexpr (OUT >= 1) {
    y0 = fmaxf(y0 + bias[fb], 0.0f);
    y1 = fmaxf(y1 + bias[fb + 1], 0.0f);
  }
  if constexpr (OUT == 2) {
    float* dp = (float*)dstv + (size_t)node * dstLd + fb;
    dp[0] = y0;
    dp[1] = y1;
  } else {
    unsigned short* dp = (unsigned short*)dstv + (size_t)node * dstLd + fb;
    ushort2 o;
    o.x = f2b(y0);
    o.y = f2b(y1);
    *(ushort2*)dp = o;
  }
}

// ---------------- bf16 MFMA GEMM, multi-segment, XCD-swizzled, LDS-XOR-swizzled ----
// MODE 0: accbuf = result + bias   MODE 1: accbuf += result
// MODE 2: dst = relu(accbuf+result) bf16 ld  MODE 3: dst = relu(accbuf+result) f32
// MODE 4: dst = relu(result+bias) bf16 ld    MODE 5: dst = relu(result+bias) f32
// MODE 6: dst = result (plain bf16, ld)

template <int MODE, int NSEG>
__global__ __launch_bounds__(256) void gemm_kernel(
    APtrs ap, const bf16* __restrict__ Bbase,
    const float* __restrict__ bias, float* __restrict__ accbuf,
    void* __restrict__ dst, int M, int Nout, int Kt, int dstLd) {
  __shared__ bf16 As[128 * 32];
  __shared__ bf16 Bs[128 * 32];
  int nb = (Nout + 127) >> 7;
  int mtiles = (M + 127) >> 7;
  int xcd = blockIdx.x & 7;
  int s = blockIdx.x >> 3;
  int bn = s % nb;
  int bm = (s / nb) * 8 + xcd;
  if (bm >= mtiles) return;
  int m0 = bm << 7, n0 = bn << 7;
  int t = threadIdx.x;
  int lane = t & 63;
  int wave = t >> 6;
  int wm = wave & 1, wn = wave >> 1;
  int l16 = lane & 15;
  int q4 = lane >> 4;
  floatx4 acc[4][4] = {};

  int srow = lane >> 2;
  int scol = (((lane & 3) ^ ((srow >> 1) & 3)) << 3);

#pragma unroll
  for (int seg = 0; seg < NSEG; seg++) {
    const bf16* A = ap.p[seg];
    const bf16* Bt = Bbase + (size_t)seg * Nout * Kt;
#pragma unroll 1
    for (int kt = 0; kt < Kt; kt += 32) {
#pragma unroll
      for (int q = 0; q < 2; q++) {
        int inst = (wave << 1) + q;
        int r = (inst << 4) + srow;
        int ga = m0 + r;
        if (ga < M)
          gl2lds16(A + (size_t)ga * Kt + kt + scol, &As[inst << 9]);
        int gb = n0 + r;
        if (gb < Nout)
          gl2lds16(Bt + (size_t)gb * Kt + kt + scol, &Bs[inst << 9]);
      }
      __syncthreads();
      shortx8 af[4], bfr[4];
#pragma unroll
      for (int i = 0; i < 4; i++) {
        int r = (wm << 6) + (i << 4) + l16;
        af[i] = *(const shortx8*)&As[(r << 5) + ((q4 ^ ((r >> 1) & 3)) << 3)];
      }
#pragma unroll
      for (int j = 0; j < 4; j++) {
        int r = (wn << 6) + (j << 4) + l16;
        bfr[j] = *(const shortx8*)&Bs[(r << 5) + ((q4 ^ ((r >> 1) & 3)) << 3)];
      }
#pragma unroll
      for (int i = 0; i < 4; i++)
#pragma unroll
        for (int j = 0; j < 4; j++)
          acc[i][j] = __builtin_amdgcn_mfma_f32_16x16x32_bf16(af[i], bfr[j], acc[i][j], 0, 0, 0);
      __syncthreads();
    }
  }

  int lq = lane >> 4;
#pragma unroll
  for (int j = 0; j < 4; j++) {
    int colg = n0 + (wn << 6) + (j << 4) + l16;
    if (colg >= Nout) continue;
    float bv = (MODE == 0 || MODE == 4 || MODE == 5) ? bias[colg] : 0.0f;
#pragma unroll
    for (int i = 0; i < 4; i++) {
      int rowb = m0 + (wm << 6) + (i << 4) + (lq << 2);
#pragma unroll
      for (int q = 0; q < 4; q++) {
        int rowg = rowb + q;
        if (rowg >= M) continue;
        float v = acc[i][j][q];
        size_t aidx = (size_t)rowg * Nout + colg;
        if constexpr (MODE == 0) {
          accbuf[aidx] = v + bv;
        } else if constexpr (MODE == 1) {
          accbuf[aidx] += v;
        } else if constexpr (MODE == 2) {
          float s2 = fmaxf(accbuf[aidx] + v, 0.0f);
          ((bf16*)dst)[(size_t)rowg * dstLd + colg] = bf16(s2);
        } else if constexpr (MODE == 3) {
          float s2 = fmaxf(accbuf[aidx] + v, 0.0f);
          ((float*)dst)[(size_t)rowg * Nout + colg] = s2;
        } else if constexpr (MODE == 4) {
          float s2 = fmaxf(v + bv, 0.0f);
          ((bf16*)dst)[(size_t)rowg * dstLd + colg] = bf16(s2);
        } else if constexpr (MODE == 5) {
          float s2 = fmaxf(v + bv, 0.0f);
          ((float*)dst)[(size_t)rowg * Nout + colg] = s2;
        } else {
          ((bf16*)dst)[(size_t)rowg * dstLd + colg] = bf16(v);
        }
      }
    }
  }
}

// ---------------- host launch ----------------

extern "C" void kernel_launch(void* const* d_in, const int* in_sizes, int n_in,
                              void* d_out, int out_size, void* d_ws, size_t ws_size,
                              hipStream_t stream) {
  const float* x = (const float*)d_in[0];
  const int* row = (const int*)d_in[1];
  const int* col = (const int*)d_in[2];
  const float* W1 = (const float*)d_in[3];
  const float* b1 = (const float*)d_in[4];
  const float* W2 = (const float*)d_in[5];
  const float* b2 = (const float*)d_in[6];
  const float* W3 = (const float*)d_in[7];
  const float* b3 = (const float*)d_in[8];

  char* ws = (char*)d_ws;
  size_t off = 0;
  auto alloc = [&](size_t bytes) -> void* {
    void* p = ws + off;
    off += (bytes + 255) & ~(size_t)255;
    return p;
  };

  const size_t TXB = (size_t)N_NODES * 1152 * 2;  // 46,080,000 (256-aligned)
  bf16* Wt = (bf16*)alloc((size_t)6 * 1152 * 1152 * 2);
  int* deg = (int*)alloc(N_NODES * 4);
  float* dis = (float*)alloc(N_NODES * 4);
  int* row_ptr = (int*)alloc((N_NODES + 1) * 4);
  int* cursor = (int*)alloc(N_NODES * 4);
  int* col_s = (int*)alloc(N_EDGES * 4);
  float* w_s = (float*)alloc(N_EDGES * 4);
  size_t off_common = off;

  size_t need_A = off_common + 7 * TXB;
  size_t need_B = off_common + 3 * TXB + (size_t)N_NODES * 1152 * 4 + 1024;
  int tier = (ws_size >= need_A) ? 0 : (ws_size >= need_B) ? 1 : 2;

  zero_kernel<<<(N_NODES + 255) / 256, 256, 0, stream>>>(deg, N_NODES);
  deg_kernel<<<(N_EDGES + 255) / 256, 256, 0, stream>>>(row, col, deg, N_EDGES);
  dis_kernel<<<(N_NODES + 255) / 256, 256, 0, stream>>>(deg, dis, N_NODES);
  scan_kernel<<<1, 1024, 0, stream>>>(deg, row_ptr, cursor, N_NODES);
  scatter_kernel<<<(N_EDGES + 255) / 256, 256, 0, stream>>>(row, col, dis, cursor,
                                                            col_s, w_s, N_EDGES);

  const int MT = (N_NODES + 127) >> 7;
  const int GMT = 8 * ((MT + 7) >> 3);  // 160
  const bf16* NB = nullptr;
  const int NX = N_NODES * 1152 / 4;

  auto prop1152 = [&](const bf16* src, const bf16* tx0, bf16* dst) {
    prop_kernel<1152, 4><<<N_NODES, 320, 0, stream>>>(row_ptr, col_s, w_s, src, tx0, dst);
  };
  auto prop576 = [&](const bf16* src, const bf16* tx0, bf16* dst) {
    prop_kernel<576, 2><<<N_NODES, 320, 0, stream>>>(row_ptr, col_s, w_s, src, tx0, dst);
  };

  if (tier == 0) {
    // ============ Tier A: layer1 forward + fused-projection Clenshaw for L2/L3 =====
    bf16* T[7];
    for (int i = 0; i < 7; i++) T[i] = (bf16*)alloc(TXB);

    // ---- layer 1: K=6, 1152 -> 1152 (forward recurrence, batched-K mega GEMM) ----
    wtrans_kernel<<<6 * 36 * 36, dim3(32, 8), 0, stream>>>(W1, Wt, 6, 1152, 1152);
    cast_x_kernel<<<(NX + 255) / 256, 256, 0, stream>>>(x, T[0], NX);
    prop1152(T[0], NB, T[1]);
    prop1152(T[1], T[0], T[2]);
    prop1152(T[2], T[1], T[3]);
    prop1152(T[3], T[2], T[4]);
    prop1152(T[4], T[3], T[5]);
    {
      APtrs a = {{T[0], T[1], T[2], T[3], T[4], T[5]}};
      gemm_kernel<4, 6><<<GMT * 9, 256, 0, stream>>>(a, Wt, b1, nullptr, T[6],
                                                     N_NODES, 1152, 1152, 1152);
    }

    // ---- layer 2: project first (g_k = h1 @ W2_k), then Clenshaw at width 576 ----
    // g2 = N x 2880 bf16 (115.2 MB) in T[0..2]; h1 = T[6]; h2 -> T[3]
    wtrans_kernel<<<5 * 36 * 18, dim3(32, 8), 0, stream>>>(W2, Wt, 5, 1152, 576);
    bf16* g2 = T[0];
    {
      APtrs a = {{T[6]}};
      gemm_kernel<6, 1><<<GMT * 23, 256, 0, stream>>>(a, Wt, b2, nullptr, g2,
                                                      N_NODES, 2880, 1152, 2880);
    }
    {
      bf16* G0 = g2;
      bf16* G1 = g2 + 576;
      bf16* G2 = g2 + 2 * 576;
      bf16* G3 = g2 + 3 * 576;
      bf16* G4 = g2 + 4 * 576;
      // b4=G4; b3 = g3 + 2L~b4 -> G3; b2 = g2 + 2L~b3 - b4 -> G2;
      // b1 = g1 + 2L~b2 - b3 -> G1; h2 = relu(g0 + L~b1 - b2 + bias) -> T[3]
      cprop_kernel<576, 2, 320, 0><<<N_NODES, 320, 0, stream>>>(
          row_ptr, col_s, w_s, G4, G3, NB, G3, 2880, 2880, 2.0f, nullptr);
      cprop_kernel<576, 2, 320, 0><<<N_NODES, 320, 0, stream>>>(
          row_ptr, col_s, w_s, G3, G2, G4, G2, 2880, 2880, 2.0f, nullptr);
      cprop_kernel<576, 2, 320, 0><<<N_NODES, 320, 0, stream>>>(
          row_ptr, col_s, w_s, G2, G1, G3, G1, 2880, 2880, 2.0f, nullptr);
      cprop_kernel<576, 2, 320, 1><<<N_NODES, 320, 0, stream>>>(
          row_ptr, col_s, w_s, G1, G0, G2, T[3], 2880, 576, 1.0f, b2);
    }

    // ---- layer 3: project (g'_k = h2 @ W3_k), Clenshaw at width 288 ----
    // g3 = N x 1440 bf16 (57.6 MB) in T[4..5]; h2 = T[3]
    wtrans_kernel<<<5 * 18 * 9, dim3(32, 8), 0, stream>>>(W3, Wt, 5, 576, 288);
    bf16* g3 = T[4];
    {
      APtrs a = {{T[3]}};
      gemm_kernel<6, 1><<<GMT * 12, 256, 0, stream>>>(a, Wt, b3, nullptr, g3,
                                                      N_NODES, 1440, 576, 1440);
    }
    {
      bf16* G0 = g3;
      bf16* G1 = g3 + 288;
      bf16* G2 = g3 + 2 * 288;
      bf16* G3 = g3 + 3 * 288;
      bf16* G4 = g3 + 4 * 288;
      cprop_kernel<288, 2, 192, 0><<<N_NODES, 192, 0, stream>>>(
          row_ptr, col_s, w_s, G4, G3, NB, G3, 1440, 1440, 2.0f, nullptr);
      cprop_kernel<288, 2, 192, 0><<<N_NODES, 192, 0, stream>>>(
          row_ptr, col_s, w_s, G3, G2, G4, G2, 1440, 1440, 2.0f, nullptr);
      cprop_kernel<288, 2, 192, 0><<<N_NODES, 192, 0, stream>>>(
          row_ptr, col_s, w_s, G2, G1, G3, G1, 1440, 1440, 2.0f, nullptr);
      cprop_kernel<288, 2, 192, 2><<<N_NODES, 192, 0, stream>>>(
          row_ptr, col_s, w_s, G1, G0, G2, d_out, 1440, 288, 1.0f, b3);
    }
    return;
  }

  // ================= Tiers B/C: rolling buffers + fp32 accbuf (fallback) ==========
  bf16* TxP = (bf16*)alloc(TXB);
  bf16* TxQ = (bf16*)alloc(TXB);
  bf16* Th = (tier == 1) ? (bf16*)alloc(TXB) : nullptr;
  float* accb = (float*)alloc((size_t)N_NODES * 1152 * 4);
  if (off > ws_size) return;

  wtrans_kernel<<<6 * 36 * 36, dim3(32, 8), 0, stream>>>(W1, Wt, 6, 1152, 1152);
  cast_x_kernel<<<(NX + 255) / 256, 256, 0, stream>>>(x, TxP, NX);
  {
    const int F = 1152, NO = 1152, nb = 9;
    size_t wsl = (size_t)NO * F;
    prop1152(TxP, NB, TxQ);
    APtrs a01 = {{TxP, TxQ}};
    gemm_kernel<0, 2><<<GMT * nb, 256, 0, stream>>>(a01, Wt, b1, accb, nullptr,
                                                    N_NODES, NO, F, 0);
    prop1152(TxQ, TxP, TxP);
    prop1152(TxP, TxQ, TxQ);
    APtrs a23 = {{TxP, TxQ}};
    gemm_kernel<1, 2><<<GMT * nb, 256, 0, stream>>>(a23, Wt + 2 * wsl, b1, accb, nullptr,
                                                    N_NODES, NO, F, 0);
    prop1152(TxQ, TxP, TxP);
    prop1152(TxP, TxQ, TxQ);
    if (tier == 1) {
      APtrs a45 = {{TxP, TxQ}};
      gemm_kernel<2, 2><<<GMT * nb, 256, 0, stream>>>(a45, Wt + 4 * wsl, b1, accb, Th,
                                                      N_NODES, NO, F, 1152);
    } else {
      APtrs a4 = {{TxP}};
      gemm_kernel<1, 1><<<GMT * nb, 256, 0, stream>>>(a4, Wt + 4 * wsl, b1, accb, nullptr,
                                                      N_NODES, NO, F, 0);
      APtrs a5 = {{TxQ}};
      gemm_kernel<2, 1><<<GMT * nb, 256, 0, stream>>>(a5, Wt + 5 * wsl, b1, accb, TxP,
                                                      N_NODES, NO, F, 1152);
    }
  }

  bf16* h1 = (tier == 1) ? Th : TxP;
  bf16* u0 = (tier == 1) ? TxP : TxQ;
  bf16* u1 = (tier == 1) ? TxQ : TxP;

  wtrans_kernel<<<5 * 36 * 18, dim3(32, 8), 0, stream>>>(W2, Wt, 5, 1152, 576);
  {
    const int F = 1152, NO = 576, nb = 5;
    size_t wsl = (size_t)NO * F;
    prop1152(h1, NB, u0);
    APtrs a01 = {{h1, u0}};
    gemm_kernel<0, 2><<<GMT * nb, 256, 0, stream>>>(a01, Wt, b2, accb, nullptr,
                                                    N_NODES, NO, F, 0);
    prop1152(u0, h1, h1);
    prop1152(h1, u0, u0);
    APtrs a23 = {{h1, u0}};
    gemm_kernel<1, 2><<<GMT * nb, 256, 0, stream>>>(a23, Wt + 2 * wsl, b2, accb, nullptr,
                                                    N_NODES, NO, F, 0);
    prop1152(u0, h1, h1);
    APtrs a4 = {{h1}};
    gemm_kernel<2, 1><<<GMT * nb, 256, 0, stream>>>(a4, Wt + 4 * wsl, b2, accb, u0,
                                                    N_NODES, NO, F, 576);
  }

  bf16* h2 = u0;

  wtrans_kernel<<<5 * 18 * 9, dim3(32, 8), 0, stream>>>(W3, Wt, 5, 576, 288);
  {
    const int F = 576, NO = 288, nb = 3;
    size_t wsl = (size_t)NO * F;
    prop576(h2, NB, u1);
    APtrs a01 = {{h2, u1}};
    gemm_kernel<0, 2><<<GMT * nb, 256, 0, stream>>>(a01, Wt, b3, accb, nullptr,
                                                    N_NODES, NO, F, 0);
    prop576(u1, h2, h2);
    prop576(h2, u1, u1);
    APtrs a23 = {{h2, u1}};
    gemm_kernel<1, 2><<<GMT * nb, 256, 0, stream>>>(a23, Wt + 2 * wsl, b3, accb, nullptr,
                                                    N_NODES, NO, F, 0);
    prop576(u1, h2, h2);
    APtrs a4 = {{h2}};
    gemm_kernel<3, 1><<<GMT * nb, 256, 0, stream>>>(a4, Wt + 4 * wsl, b3, accb, d_out,
                                                    N_NODES, NO, F, 0);
  }
}